// Round 1
// baseline (847.089 us; speedup 1.0000x reference)
//
#include <hip/hip_runtime.h>
#include <hip/hip_bf16.h>

#define CIN 192
#define C3 576
#define HWPX 16384
#define NHEADS 4
#define DH 48

__device__ __forceinline__ float bf2f(unsigned short u) {
    return __uint_as_float(((unsigned int)u) << 16);
}
__device__ __forceinline__ unsigned short f2bf(float f) {
    unsigned int u = __float_as_uint(f);
    unsigned int r = (u >> 16) & 1u;
    u += 0x7fffu + r;
    return (unsigned short)(u >> 16);
}

// ---------------------------------------------------------------------------
// K1: qkv = qkv_w @ x  (per batch: [576,192] @ [192,16384]), fp32 in, bf16 out
// tile 64(o) x 256(p), BK=32, 256 thr, 8x8 per thread
// ---------------------------------------------------------------------------
__global__ __launch_bounds__(256) void k_qkv(const float* __restrict__ x,
                                             const float* __restrict__ w,
                                             unsigned short* __restrict__ pre) {
    __shared__ float sw[32][64];
    __shared__ float sx[32][256];
    const int t = threadIdx.x;
    const int p0 = blockIdx.x * 256;
    const int o0 = blockIdx.y * 64;
    const int b = blockIdx.z;
    const float* xb = x + (size_t)b * CIN * HWPX;
    float acc[8][8];
#pragma unroll
    for (int i = 0; i < 8; ++i)
#pragma unroll
        for (int j = 0; j < 8; ++j) acc[i][j] = 0.f;
    const int tm = t >> 5, tn = t & 31;
    for (int kc = 0; kc < CIN; kc += 32) {
#pragma unroll
        for (int r = 0; r < 2; ++r) {
            int f = t + r * 256;
            int m = f >> 3, k4 = f & 7;
            float4 wv = *(const float4*)(w + (size_t)(o0 + m) * CIN + kc + k4 * 4);
            sw[k4 * 4 + 0][m] = wv.x;
            sw[k4 * 4 + 1][m] = wv.y;
            sw[k4 * 4 + 2][m] = wv.z;
            sw[k4 * 4 + 3][m] = wv.w;
        }
#pragma unroll
        for (int r = 0; r < 8; ++r) {
            int f = t + r * 256;
            int k = f >> 6, n4 = f & 63;
            *(float4*)(&sx[k][n4 * 4]) =
                *(const float4*)(xb + (size_t)(kc + k) * HWPX + p0 + n4 * 4);
        }
        __syncthreads();
#pragma unroll
        for (int k = 0; k < 32; ++k) {
            float a[8], bb[8];
#pragma unroll
            for (int i = 0; i < 8; ++i) a[i] = sw[k][tm * 8 + i];
#pragma unroll
            for (int j = 0; j < 8; ++j) bb[j] = sx[k][tn * 8 + j];
#pragma unroll
            for (int i = 0; i < 8; ++i)
#pragma unroll
                for (int j = 0; j < 8; ++j) acc[i][j] = fmaf(a[i], bb[j], acc[i][j]);
        }
        __syncthreads();
    }
#pragma unroll
    for (int i = 0; i < 8; ++i) {
        unsigned int pk[4];
#pragma unroll
        for (int j2 = 0; j2 < 4; ++j2)
            pk[j2] = (unsigned int)f2bf(acc[i][2 * j2]) |
                     ((unsigned int)f2bf(acc[i][2 * j2 + 1]) << 16);
        size_t off = ((size_t)b * C3 + o0 + tm * 8 + i) * HWPX + p0 + tn * 8;
        *(uint4*)(pre + off) = make_uint4(pk[0], pk[1], pk[2], pk[3]);
    }
}

// ---------------------------------------------------------------------------
// K2: depthwise 3x3 SAME + fused per-channel sum of squares (exact fp32)
// one block per (b,ch) plane; plane staged in LDS (32 KB bf16)
// ---------------------------------------------------------------------------
__global__ __launch_bounds__(256) void k_dw(const unsigned short* __restrict__ pre,
                                            const float* __restrict__ dww,
                                            unsigned short* __restrict__ dwout,
                                            float* __restrict__ norm2) {
    __shared__ unsigned short tile[HWPX];
    __shared__ float red[256];
    const int ch = blockIdx.x, b = blockIdx.y;
    const int t = threadIdx.x;
    const unsigned short* in = pre + ((size_t)b * C3 + ch) * HWPX;
    unsigned short* outp = dwout + ((size_t)b * C3 + ch) * HWPX;
    float w[9];
#pragma unroll
    for (int i = 0; i < 9; ++i) w[i] = dww[ch * 9 + i];
#pragma unroll
    for (int r = 0; r < 8; ++r) {
        int f = t + r * 256;
        *(uint4*)(tile + f * 8) = *(const uint4*)(in + f * 8);
    }
    __syncthreads();
    float ssq = 0.f;
    for (int r = 0; r < 64; ++r) {
        int p = r * 256 + t;
        int y = p >> 7, xx = p & 127;
        float s = 0.f;
#pragma unroll
        for (int ky = 0; ky < 3; ++ky) {
            int yy = y + ky - 1;
            if (yy < 0 || yy > 127) continue;
#pragma unroll
            for (int kx = 0; kx < 3; ++kx) {
                int xv = xx + kx - 1;
                if (xv < 0 || xv > 127) continue;
                s = fmaf(w[ky * 3 + kx], bf2f(tile[yy * 128 + xv]), s);
            }
        }
        outp[p] = f2bf(s);
        ssq += s * s;
    }
    red[t] = ssq;
    __syncthreads();
    for (int s2 = 128; s2 > 0; s2 >>= 1) {
        if (t < s2) red[t] += red[t + s2];
        __syncthreads();
    }
    if (t == 0) norm2[b * C3 + ch] = red[0];
}

// ---------------------------------------------------------------------------
// K3: raw gram partials G[c,d] = sum_p q_c[p] k_d[p] over a 2048-pixel chunk
// grid (chunk=8, head=4, batch=8); 48x48 out per (b,h), 3x3 per thread
// ---------------------------------------------------------------------------
__global__ __launch_bounds__(256) void k_gram(const unsigned short* __restrict__ qkv_dw,
                                              float* __restrict__ gpart) {
    __shared__ float qs[48][129];
    __shared__ float ks2[48][129];
    const int chunk = blockIdx.x, h = blockIdx.y, b = blockIdx.z;
    const int t = threadIdx.x;
    const int P0 = chunk * 2048;
    const unsigned short* qb = qkv_dw + ((size_t)b * C3 + h * DH) * HWPX;
    const unsigned short* kb = qkv_dw + ((size_t)b * C3 + CIN + h * DH) * HWPX;
    const int c0 = (t >> 4) * 3, d0 = (t & 15) * 3;
    float acc[3][3];
#pragma unroll
    for (int i = 0; i < 3; ++i)
#pragma unroll
        for (int j = 0; j < 3; ++j) acc[i][j] = 0.f;
    for (int pt = 0; pt < 2048; pt += 128) {
#pragma unroll
        for (int r = 0; r < 3; ++r) {
            int f = t + r * 256;  // 0..767
            int row = f >> 4, col8 = f & 15;
            uint4 v = *(const uint4*)(qb + (size_t)row * HWPX + P0 + pt + col8 * 8);
            unsigned int uu[4] = {v.x, v.y, v.z, v.w};
#pragma unroll
            for (int q = 0; q < 4; ++q) {
                qs[row][col8 * 8 + 2 * q] = __uint_as_float(uu[q] << 16);
                qs[row][col8 * 8 + 2 * q + 1] = __uint_as_float(uu[q] & 0xffff0000u);
            }
            uint4 v2 = *(const uint4*)(kb + (size_t)row * HWPX + P0 + pt + col8 * 8);
            unsigned int u2[4] = {v2.x, v2.y, v2.z, v2.w};
#pragma unroll
            for (int q = 0; q < 4; ++q) {
                ks2[row][col8 * 8 + 2 * q] = __uint_as_float(u2[q] << 16);
                ks2[row][col8 * 8 + 2 * q + 1] = __uint_as_float(u2[q] & 0xffff0000u);
            }
        }
        __syncthreads();
        for (int p = 0; p < 128; ++p) {
            float qv[3], kv[3];
#pragma unroll
            for (int i = 0; i < 3; ++i) qv[i] = qs[c0 + i][p];
#pragma unroll
            for (int j = 0; j < 3; ++j) kv[j] = ks2[d0 + j][p];
#pragma unroll
            for (int i = 0; i < 3; ++i)
#pragma unroll
                for (int j = 0; j < 3; ++j) acc[i][j] = fmaf(qv[i], kv[j], acc[i][j]);
        }
        __syncthreads();
    }
    float* g = gpart + (((size_t)(b * NHEADS + h)) * 8 + chunk) * (DH * DH);
#pragma unroll
    for (int i = 0; i < 3; ++i)
#pragma unroll
        for (int j = 0; j < 3; ++j) g[(c0 + i) * DH + d0 + j] = acc[i][j];
}

// ---------------------------------------------------------------------------
// K4: reduce gram partials -> normalize -> *temperature -> softmax ->
//     M_b = proj_w @ blockdiag(attn)   (one block per batch)
// ---------------------------------------------------------------------------
__global__ __launch_bounds__(256) void k_attn_mat(const float* __restrict__ gpart,
                                                  const float* __restrict__ norm2,
                                                  const float* __restrict__ proj_w,
                                                  const float* __restrict__ temperature,
                                                  float* __restrict__ Mw) {
    __shared__ float att[NHEADS][DH][DH];
    const int b = blockIdx.x;
    const int t = threadIdx.x;
    for (int r = 0; r < 36; ++r) {
        int e = t + r * 256;  // 0..9215
        int h = e / (DH * DH), cd = e % (DH * DH);
        int c = cd / DH, d = cd % DH;
        const float* gp = gpart + ((size_t)(b * NHEADS + h) * 8) * (DH * DH) + cd;
        float s = 0.f;
#pragma unroll
        for (int ch = 0; ch < 8; ++ch) s += gp[(size_t)ch * (DH * DH)];
        float nq = fmaxf(sqrtf(norm2[b * C3 + h * DH + c]), 1e-12f);
        float nk = fmaxf(sqrtf(norm2[b * C3 + CIN + h * DH + d]), 1e-12f);
        att[h][c][d] = s / (nq * nk) * temperature[h];
    }
    __syncthreads();
    if (t < NHEADS * DH) {
        int h = t / DH, c = t % DH;
        float row[DH];
        float m = -1e30f;
#pragma unroll
        for (int d = 0; d < DH; ++d) {
            row[d] = att[h][c][d];
            m = fmaxf(m, row[d]);
        }
        float s = 0.f;
#pragma unroll
        for (int d = 0; d < DH; ++d) {
            row[d] = expf(row[d] - m);
            s += row[d];
        }
        float inv = 1.f / s;
#pragma unroll
        for (int d = 0; d < DH; ++d) att[h][c][d] = row[d] * inv;
    }
    __syncthreads();
    for (int r = 0; r < 144; ++r) {
        int e = t + r * 256;  // 0..36863
        int o = e / CIN, dg = e % CIN;
        int h = dg / DH, d = dg % DH;
        const float* pw = proj_w + (size_t)o * CIN + h * DH;
        float s = 0.f;
#pragma unroll
        for (int c = 0; c < DH; ++c) s = fmaf(pw[c], att[h][c][d], s);
        Mw[(size_t)b * CIN * CIN + e] = s;
    }
}

// ---------------------------------------------------------------------------
// K5: out = M_b @ v  (per batch [192,192] @ [192,16384]), bf16 v, fp32 out
// ---------------------------------------------------------------------------
__global__ __launch_bounds__(256) void k_out(const float* __restrict__ Mw,
                                             const unsigned short* __restrict__ qkv_dw,
                                             float* __restrict__ out) {
    __shared__ float sw[32][64];
    __shared__ float sx[32][256];
    const int t = threadIdx.x;
    const int p0 = blockIdx.x * 256;
    const int o0 = blockIdx.y * 64;
    const int b = blockIdx.z;
    const float* wb = Mw + (size_t)b * CIN * CIN;
    const unsigned short* vb = qkv_dw + ((size_t)b * C3 + 2 * CIN) * HWPX;
    float acc[8][8];
#pragma unroll
    for (int i = 0; i < 8; ++i)
#pragma unroll
        for (int j = 0; j < 8; ++j) acc[i][j] = 0.f;
    const int tm = t >> 5, tn = t & 31;
    for (int kc = 0; kc < CIN; kc += 32) {
#pragma unroll
        for (int r = 0; r < 2; ++r) {
            int f = t + r * 256;
            int m = f >> 3, k4 = f & 7;
            float4 wv = *(const float4*)(wb + (size_t)(o0 + m) * CIN + kc + k4 * 4);
            sw[k4 * 4 + 0][m] = wv.x;
            sw[k4 * 4 + 1][m] = wv.y;
            sw[k4 * 4 + 2][m] = wv.z;
            sw[k4 * 4 + 3][m] = wv.w;
        }
#pragma unroll
        for (int r = 0; r < 4; ++r) {
            int f = t + r * 256;  // 0..1023
            int k = f >> 5, n8 = f & 31;
            uint4 v = *(const uint4*)(vb + (size_t)(kc + k) * HWPX + p0 + n8 * 8);
            unsigned int uu[4] = {v.x, v.y, v.z, v.w};
#pragma unroll
            for (int q = 0; q < 4; ++q) {
                sx[k][n8 * 8 + 2 * q] = __uint_as_float(uu[q] << 16);
                sx[k][n8 * 8 + 2 * q + 1] = __uint_as_float(uu[q] & 0xffff0000u);
            }
        }
        __syncthreads();
#pragma unroll
        for (int k = 0; k < 32; ++k) {
            float a[8], bb[8];
#pragma unroll
            for (int i = 0; i < 8; ++i) a[i] = sw[k][tm * 8 + i];
#pragma unroll
            for (int j = 0; j < 8; ++j) bb[j] = sx[k][tn * 8 + j];
#pragma unroll
            for (int i = 0; i < 8; ++i)
#pragma unroll
                for (int j = 0; j < 8; ++j) acc[i][j] = fmaf(a[i], bb[j], acc[i][j]);
        }
        __syncthreads();
    }
#pragma unroll
    for (int i = 0; i < 8; ++i) {
        size_t off = ((size_t)b * CIN + o0 + tm * 8 + i) * HWPX + p0 + tn * 8;
        *(float4*)(out + off) = make_float4(acc[i][0], acc[i][1], acc[i][2], acc[i][3]);
        *(float4*)(out + off + 4) = make_float4(acc[i][4], acc[i][5], acc[i][6], acc[i][7]);
    }
}

extern "C" void kernel_launch(void* const* d_in, const int* in_sizes, int n_in,
                              void* d_out, int out_size, void* d_ws, size_t ws_size,
                              hipStream_t stream) {
    const float* x = (const float*)d_in[0];
    const float* qkv_w = (const float*)d_in[1];
    const float* dw_w = (const float*)d_in[2];
    const float* proj_w = (const float*)d_in[3];
    const float* temperature = (const float*)d_in[4];
    float* out = (float*)d_out;

    char* ws = (char*)d_ws;
    // layout (bytes):
    //   [0, 150994944)              qkv_pre  bf16  8*576*16384
    //   [150994944, 301989888)      qkv_dw   bf16
    //   [301989888, +18KB)          norm2    fp32  8*576
    //   [302022656, +2359296)       gpart    fp32  8*4*8*48*48
    //   [304381952, +1179648)       Mw       fp32  8*192*192
    unsigned short* pre = (unsigned short*)ws;
    unsigned short* dw = (unsigned short*)(ws + 150994944);
    float* norm2 = (float*)(ws + 301989888);
    float* gpart = (float*)(ws + 302022656);
    float* Mw = (float*)(ws + 304381952);

    k_qkv<<<dim3(64, 9, 8), 256, 0, stream>>>(x, qkv_w, pre);
    k_dw<<<dim3(576, 8), 256, 0, stream>>>(pre, dw_w, dw, norm2);
    k_gram<<<dim3(8, 4, 8), 256, 0, stream>>>(dw, gpart);
    k_attn_mat<<<8, 256, 0, stream>>>(gpart, norm2, proj_w, temperature, Mw);
    k_out<<<dim3(64, 3, 8), 256, 0, stream>>>(Mw, dw, out);
}

// Round 2
// 595.836 us; speedup vs baseline: 1.4217x; 1.4217x over previous
//
#include <hip/hip_runtime.h>
#include <hip/hip_bf16.h>

#define CIN 192
#define C3 576
#define HWPX 16384
#define NHEADS 4
#define DH 48

typedef unsigned short ushort_t;
typedef __attribute__((ext_vector_type(8))) short bf16x8;
typedef __attribute__((ext_vector_type(4))) float f32x4;

__device__ __forceinline__ float bf2f(unsigned short u) {
    return __uint_as_float(((unsigned int)u) << 16);
}
__device__ __forceinline__ unsigned short f2bf(float f) {
    unsigned int u = __float_as_uint(f);
    unsigned int r = (u >> 16) & 1u;
    u += 0x7fffu + r;
    return (unsigned short)(u >> 16);
}

#define ASYNC_COPY16(gptr, lptr)                                                   \
    __builtin_amdgcn_global_load_lds(                                              \
        (__attribute__((address_space(1))) void*)(gptr),                           \
        (__attribute__((address_space(3))) void*)(lptr), 16, 0, 0)

// ---------------------------------------------------------------------------
// k_cvtw: qkv_w fp32 [576,192] -> bf16 (row-major, K-contiguous)
// ---------------------------------------------------------------------------
__global__ __launch_bounds__(256) void k_cvtw(const float* __restrict__ w,
                                              ushort_t* __restrict__ wb) {
    int i = (blockIdx.x * 256 + threadIdx.x) * 4;  // 110592 elems / 4
    float4 v = *(const float4*)(w + i);
    ushort_t o0 = f2bf(v.x), o1 = f2bf(v.y), o2 = f2bf(v.z), o3 = f2bf(v.w);
    uint2 pk;
    pk.x = (unsigned)o0 | ((unsigned)o1 << 16);
    pk.y = (unsigned)o2 | ((unsigned)o3 << 16);
    *(uint2*)(wb + i) = pk;
}

// ---------------------------------------------------------------------------
// k_xt: x fp32 [b][192][16384] -> xT bf16 [b][16384][192]
// ---------------------------------------------------------------------------
__global__ __launch_bounds__(256) void k_xt(const float* __restrict__ x,
                                            ushort_t* __restrict__ xT) {
    __shared__ ushort_t tile[64][200];
    const int t = threadIdx.x;
    const int pix0 = blockIdx.x * 64;
    const int b = blockIdx.y;
    const float* xb = x + (size_t)b * CIN * HWPX;
#pragma unroll 4
    for (int r = 0; r < 48; ++r) {
        int ch = r * 4 + (t >> 6);
        float v = xb[(size_t)ch * HWPX + pix0 + (t & 63)];
        tile[t & 63][ch] = f2bf(v);
    }
    __syncthreads();
    ushort_t* xTb = xT + ((size_t)b * HWPX + pix0) * CIN;
#pragma unroll
    for (int r = 0; r < 6; ++r) {
        int idx = r * 256 + t;
        int row = idx / 24, cc = (idx % 24) * 8;
        uint4 v = *(const uint4*)&tile[row][cc];
        *(uint4*)(xTb + (size_t)row * CIN + cc) = v;
    }
}

// ---------------------------------------------------------------------------
// k_vt: dw v-section bf16 [b][ch][16384] -> vT bf16 [b][16384][192]
// ---------------------------------------------------------------------------
__global__ __launch_bounds__(256) void k_vt(const ushort_t* __restrict__ dwv,
                                            ushort_t* __restrict__ vT) {
    __shared__ ushort_t tile[64][200];
    const int t = threadIdx.x;
    const int pix0 = blockIdx.x * 64;
    const int b = blockIdx.y;
    const ushort_t* vb = dwv + ((size_t)b * C3 + 2 * CIN) * HWPX;
#pragma unroll 4
    for (int r = 0; r < 24; ++r) {
        int ch = r * 8 + (t >> 5);
        int pix = (t & 31) * 2;
        unsigned v = *(const unsigned*)(vb + (size_t)ch * HWPX + pix0 + pix);
        tile[pix][ch] = (ushort_t)v;
        tile[pix + 1][ch] = (ushort_t)(v >> 16);
    }
    __syncthreads();
    ushort_t* vTb = vT + ((size_t)b * HWPX + pix0) * CIN;
#pragma unroll
    for (int r = 0; r < 6; ++r) {
        int idx = r * 256 + t;
        int row = idx / 24, cc = (idx % 24) * 8;
        uint4 v = *(const uint4*)&tile[row][cc];
        *(uint4*)(vTb + (size_t)row * CIN + cc) = v;
    }
}

// ---------------------------------------------------------------------------
// k_gemm: D[pix][o] = sum_k A[pix][k] * B[o][k]
//   A: bf16 [16384][192] per batch (xT or vT)
//   B: bf16 [O][192] (qkv_w bf16, strideB=0 shared; or Mw per batch)
//   C: [O][16384] per batch, bf16 (pre) or fp32 (out)
// tile: BM=256 pix x BN=64 o, 4 waves (each 64x64), BK=32, double-buffered,
// global_load_lds w/ inverse-swizzled source (chunk' = (chunk+(row>>1))&3)
// ---------------------------------------------------------------------------
template <bool OUT_BF16>
__global__ __launch_bounds__(256) void k_gemm(const ushort_t* __restrict__ A,
                                              const ushort_t* __restrict__ B,
                                              void* __restrict__ C,
                                              long strideA, long strideB, long strideC) {
    __shared__ ushort_t sA[2][256 * 32];
    __shared__ ushort_t sB[2][64 * 32];
    const int t = threadIdx.x;
    const int lane = t & 63, wave = t >> 6;
    const int o0 = blockIdx.x * 64;
    const int pix0 = blockIdx.y * 256;
    const int b = blockIdx.z;
    const ushort_t* Ab = A + (size_t)b * strideA + (size_t)pix0 * CIN;
    const ushort_t* Bb = B + (size_t)b * strideB + (size_t)o0 * CIN;

    f32x4 acc[4][4];
#pragma unroll
    for (int mi = 0; mi < 4; ++mi)
#pragma unroll
        for (int ni = 0; ni < 4; ++ni) acc[mi][ni] = (f32x4){0.f, 0.f, 0.f, 0.f};

    auto stage = [&](int buf, int k0) {
#pragma unroll
        for (int c2 = 0; c2 < 4; ++c2) {
            int e = c2 * 256 + t;
            int row = e >> 2, slot = e & 3;
            int g = (slot + (row >> 1)) & 3;
            const ushort_t* gp = Ab + (size_t)row * CIN + k0 + g * 8;
            ushort_t* lp = &sA[buf][(c2 * 256 + wave * 64) * 8];
            ASYNC_COPY16(gp, lp);
        }
        {
            int row = t >> 2, slot = t & 3;
            int g = (slot + (row >> 1)) & 3;
            const ushort_t* gp = Bb + (size_t)row * CIN + k0 + g * 8;
            ushort_t* lp = &sB[buf][(wave * 64) * 8];
            ASYNC_COPY16(gp, lp);
        }
    };

    stage(0, 0);
#pragma unroll
    for (int ks = 0; ks < 6; ++ks) {
        __syncthreads();
        if (ks < 5) stage((ks + 1) & 1, (ks + 1) * 32);
        const ushort_t* a_ = sA[ks & 1];
        const ushort_t* b_ = sB[ks & 1];
        const int c = lane >> 4;
        bf16x8 af[4], bfr[4];
#pragma unroll
        for (int mi = 0; mi < 4; ++mi) {
            int row = wave * 64 + mi * 16 + (lane & 15);
            int slot = (c - (row >> 1)) & 3;
            af[mi] = *(const bf16x8*)&a_[row * 32 + slot * 8];
        }
#pragma unroll
        for (int ni = 0; ni < 4; ++ni) {
            int row = ni * 16 + (lane & 15);
            int slot = (c - (row >> 1)) & 3;
            bfr[ni] = *(const bf16x8*)&b_[row * 32 + slot * 8];
        }
#pragma unroll
        for (int mi = 0; mi < 4; ++mi)
#pragma unroll
            for (int ni = 0; ni < 4; ++ni)
                acc[mi][ni] = __builtin_amdgcn_mfma_f32_16x16x32_bf16(
                    af[mi], bfr[ni], acc[mi][ni], 0, 0, 0);
    }

    const int ocol = lane & 15;
    const int prow = (lane >> 4) * 4;
#pragma unroll
    for (int mi = 0; mi < 4; ++mi) {
        int pix = pix0 + wave * 64 + mi * 16 + prow;
#pragma unroll
        for (int ni = 0; ni < 4; ++ni) {
            int o = o0 + ni * 16 + ocol;
            f32x4 v = acc[mi][ni];
            if constexpr (OUT_BF16) {
                ushort_t* Cp = (ushort_t*)C + (size_t)b * strideC + (size_t)o * HWPX + pix;
                uint2 pk;
                pk.x = (unsigned)f2bf(v[0]) | ((unsigned)f2bf(v[1]) << 16);
                pk.y = (unsigned)f2bf(v[2]) | ((unsigned)f2bf(v[3]) << 16);
                *(uint2*)Cp = pk;
            } else {
                float* Cp = (float*)C + (size_t)b * strideC + (size_t)o * HWPX + pix;
                *(float4*)Cp = make_float4(v[0], v[1], v[2], v[3]);
            }
        }
    }
}

// ---------------------------------------------------------------------------
// k_dw: depthwise 3x3 SAME + fused per-channel sum of squares (exact fp32)
// ---------------------------------------------------------------------------
__global__ __launch_bounds__(256) void k_dw(const ushort_t* __restrict__ pre,
                                            const float* __restrict__ dww,
                                            ushort_t* __restrict__ dwout,
                                            float* __restrict__ norm2) {
    __shared__ ushort_t tile[HWPX];
    __shared__ float red[256];
    const int ch = blockIdx.x, b = blockIdx.y;
    const int t = threadIdx.x;
    const ushort_t* in = pre + ((size_t)b * C3 + ch) * HWPX;
    ushort_t* outp = dwout + ((size_t)b * C3 + ch) * HWPX;
    float w[9];
#pragma unroll
    for (int i = 0; i < 9; ++i) w[i] = dww[ch * 9 + i];
#pragma unroll
    for (int r = 0; r < 8; ++r) {
        int f = t + r * 256;
        *(uint4*)(tile + f * 8) = *(const uint4*)(in + f * 8);
    }
    __syncthreads();
    float ssq = 0.f;
    for (int r = 0; r < 64; ++r) {
        int p = r * 256 + t;
        int y = p >> 7, xx = p & 127;
        float s = 0.f;
#pragma unroll
        for (int ky = 0; ky < 3; ++ky) {
            int yy = y + ky - 1;
            if (yy < 0 || yy > 127) continue;
#pragma unroll
            for (int kx = 0; kx < 3; ++kx) {
                int xv = xx + kx - 1;
                if (xv < 0 || xv > 127) continue;
                s = fmaf(w[ky * 3 + kx], bf2f(tile[yy * 128 + xv]), s);
            }
        }
        outp[p] = f2bf(s);
        ssq += s * s;
    }
    red[t] = ssq;
    __syncthreads();
    for (int s2 = 128; s2 > 0; s2 >>= 1) {
        if (t < s2) red[t] += red[t + s2];
        __syncthreads();
    }
    if (t == 0) norm2[b * C3 + ch] = red[0];
}

// ---------------------------------------------------------------------------
// k_gram: raw gram partials over 2048-pixel chunks
// ---------------------------------------------------------------------------
__global__ __launch_bounds__(256) void k_gram(const ushort_t* __restrict__ qkv_dw,
                                              float* __restrict__ gpart) {
    __shared__ float qs[48][129];
    __shared__ float ks2[48][129];
    const int chunk = blockIdx.x, h = blockIdx.y, b = blockIdx.z;
    const int t = threadIdx.x;
    const int P0 = chunk * 2048;
    const ushort_t* qb = qkv_dw + ((size_t)b * C3 + h * DH) * HWPX;
    const ushort_t* kb = qkv_dw + ((size_t)b * C3 + CIN + h * DH) * HWPX;
    const int c0 = (t >> 4) * 3, d0 = (t & 15) * 3;
    float acc[3][3];
#pragma unroll
    for (int i = 0; i < 3; ++i)
#pragma unroll
        for (int j = 0; j < 3; ++j) acc[i][j] = 0.f;
    for (int pt = 0; pt < 2048; pt += 128) {
#pragma unroll
        for (int r = 0; r < 3; ++r) {
            int f = t + r * 256;
            int row = f >> 4, col8 = f & 15;
            uint4 v = *(const uint4*)(qb + (size_t)row * HWPX + P0 + pt + col8 * 8);
            unsigned int uu[4] = {v.x, v.y, v.z, v.w};
#pragma unroll
            for (int q = 0; q < 4; ++q) {
                qs[row][col8 * 8 + 2 * q] = __uint_as_float(uu[q] << 16);
                qs[row][col8 * 8 + 2 * q + 1] = __uint_as_float(uu[q] & 0xffff0000u);
            }
            uint4 v2 = *(const uint4*)(kb + (size_t)row * HWPX + P0 + pt + col8 * 8);
            unsigned int u2[4] = {v2.x, v2.y, v2.z, v2.w};
#pragma unroll
            for (int q = 0; q < 4; ++q) {
                ks2[row][col8 * 8 + 2 * q] = __uint_as_float(u2[q] << 16);
                ks2[row][col8 * 8 + 2 * q + 1] = __uint_as_float(u2[q] & 0xffff0000u);
            }
        }
        __syncthreads();
        for (int p = 0; p < 128; ++p) {
            float qv[3], kv[3];
#pragma unroll
            for (int i = 0; i < 3; ++i) qv[i] = qs[c0 + i][p];
#pragma unroll
            for (int j = 0; j < 3; ++j) kv[j] = ks2[d0 + j][p];
#pragma unroll
            for (int i = 0; i < 3; ++i)
#pragma unroll
                for (int j = 0; j < 3; ++j) acc[i][j] = fmaf(qv[i], kv[j], acc[i][j]);
        }
        __syncthreads();
    }
    float* g = gpart + (((size_t)(b * NHEADS + h)) * 8 + chunk) * (DH * DH);
#pragma unroll
    for (int i = 0; i < 3; ++i)
#pragma unroll
        for (int j = 0; j < 3; ++j) g[(c0 + i) * DH + d0 + j] = acc[i][j];
}

// ---------------------------------------------------------------------------
// k_attn_mat: reduce -> normalize -> softmax -> Mw = proj_w @ blockdiag(attn)
// Mw written bf16 row-major [o][ch]
// ---------------------------------------------------------------------------
__global__ __launch_bounds__(256) void k_attn_mat(const float* __restrict__ gpart,
                                                  const float* __restrict__ norm2,
                                                  const float* __restrict__ proj_w,
                                                  const float* __restrict__ temperature,
                                                  ushort_t* __restrict__ Mw) {
    __shared__ float att[NHEADS][DH][DH];
    const int b = blockIdx.x;
    const int t = threadIdx.x;
    for (int r = 0; r < 36; ++r) {
        int e = t + r * 256;
        int h = e / (DH * DH), cd = e % (DH * DH);
        int c = cd / DH, d = cd % DH;
        const float* gp = gpart + ((size_t)(b * NHEADS + h) * 8) * (DH * DH) + cd;
        float s = 0.f;
#pragma unroll
        for (int ch = 0; ch < 8; ++ch) s += gp[(size_t)ch * (DH * DH)];
        float nq = fmaxf(sqrtf(norm2[b * C3 + h * DH + c]), 1e-12f);
        float nk = fmaxf(sqrtf(norm2[b * C3 + CIN + h * DH + d]), 1e-12f);
        att[h][c][d] = s / (nq * nk) * temperature[h];
    }
    __syncthreads();
    if (t < NHEADS * DH) {
        int h = t / DH, c = t % DH;
        float row[DH];
        float m = -1e30f;
#pragma unroll
        for (int d = 0; d < DH; ++d) {
            row[d] = att[h][c][d];
            m = fmaxf(m, row[d]);
        }
        float s = 0.f;
#pragma unroll
        for (int d = 0; d < DH; ++d) {
            row[d] = expf(row[d] - m);
            s += row[d];
        }
        float inv = 1.f / s;
#pragma unroll
        for (int d = 0; d < DH; ++d) att[h][c][d] = row[d] * inv;
    }
    __syncthreads();
    for (int r = 0; r < 144; ++r) {
        int e = t + r * 256;
        int o = e / CIN, dg = e % CIN;
        int h = dg / DH, d = dg % DH;
        const float* pw = proj_w + (size_t)o * CIN + h * DH;
        float s = 0.f;
#pragma unroll
        for (int c = 0; c < DH; ++c) s = fmaf(pw[c], att[h][c][d], s);
        Mw[(size_t)b * CIN * CIN + e] = f2bf(s);
    }
}

extern "C" void kernel_launch(void* const* d_in, const int* in_sizes, int n_in,
                              void* d_out, int out_size, void* d_ws, size_t ws_size,
                              hipStream_t stream) {
    const float* x = (const float*)d_in[0];
    const float* qkv_w = (const float*)d_in[1];
    const float* dw_w = (const float*)d_in[2];
    const float* proj_w = (const float*)d_in[3];
    const float* temperature = (const float*)d_in[4];
    float* out = (float*)d_out;

    char* ws = (char*)d_ws;
    // layout (bytes), overlays keep footprint <= 305.2 MB:
    //   [0, 150994944)           pre  bf16   -> later vT bf16 (overlay, pre dead)
    //   [150994944, 301989888)   dw   bf16   ; xT bf16 temporarily at rear
    //   xT @ 251658240 (50331648 B, dead before k_dw writes its region)
    //   [301989888, +221184)     wq bf16
    //   [302211072, +18432)      norm2 fp32
    //   [302229504, +2359296)    gpart fp32
    //   [304588800, +589824)     Mw bf16
    ushort_t* pre = (ushort_t*)ws;
    ushort_t* vT = (ushort_t*)ws;  // overlays pre
    ushort_t* dwv = (ushort_t*)(ws + 150994944);
    ushort_t* xT = (ushort_t*)(ws + 251658240);
    ushort_t* wq = (ushort_t*)(ws + 301989888);
    float* norm2 = (float*)(ws + 302211072);
    float* gpart = (float*)(ws + 302229504);
    ushort_t* Mw = (ushort_t*)(ws + 304588800);

    const long sA = (long)HWPX * CIN;           // 3145728
    const long sC_pre = (long)C3 * HWPX;        // 9437184
    const long sB_mw = (long)CIN * CIN;         // 36864
    const long sC_out = (long)CIN * HWPX;       // 3145728

    k_cvtw<<<dim3(108), 256, 0, stream>>>(qkv_w, wq);
    k_xt<<<dim3(256, 8), 256, 0, stream>>>(x, xT);
    k_gemm<true><<<dim3(9, 64, 8), 256, 0, stream>>>(xT, wq, (void*)pre, sA, 0L, sC_pre);
    k_dw<<<dim3(576, 8), 256, 0, stream>>>(pre, dw_w, dwv, norm2);
    k_gram<<<dim3(8, 4, 8), 256, 0, stream>>>(dwv, gpart);
    k_attn_mat<<<8, 256, 0, stream>>>(gpart, norm2, proj_w, temperature, Mw);
    k_vt<<<dim3(256, 8), 256, 0, stream>>>(dwv, vT);
    k_gemm<false><<<dim3(3, 64, 8), 256, 0, stream>>>(vT, Mw, (void*)out, sA, sB_mw, sC_out);
}

// Round 3
// 328.145 us; speedup vs baseline: 2.5814x; 1.8158x over previous
//
#include <hip/hip_runtime.h>
#include <hip/hip_bf16.h>

#define CIN 192
#define C3 576
#define HWPX 16384
#define NHEADS 4
#define DH 48

typedef unsigned short ushort_t;
typedef __attribute__((ext_vector_type(8))) short bf16x8;
typedef __attribute__((ext_vector_type(4))) float f32x4;

__device__ __forceinline__ float bf2f(unsigned short u) {
    return __uint_as_float(((unsigned int)u) << 16);
}
__device__ __forceinline__ unsigned short f2bf(float f) {
    unsigned int u = __float_as_uint(f);
    unsigned int r = (u >> 16) & 1u;
    u += 0x7fffu + r;
    return (unsigned short)(u >> 16);
}

#define ASYNC_COPY16(gptr, lptr)                                                   \
    __builtin_amdgcn_global_load_lds(                                              \
        (__attribute__((address_space(1))) void*)(gptr),                           \
        (__attribute__((address_space(3))) void*)(lptr), 16, 0, 0)

// ---------------------------------------------------------------------------
// k_cvtw: qkv_w fp32 [576,192] -> bf16 row-major
// ---------------------------------------------------------------------------
__global__ __launch_bounds__(256) void k_cvtw(const float* __restrict__ w,
                                              ushort_t* __restrict__ wb) {
    int i = (blockIdx.x * 256 + threadIdx.x) * 4;
    float4 v = *(const float4*)(w + i);
    uint2 pk;
    pk.x = (unsigned)f2bf(v.x) | ((unsigned)f2bf(v.y) << 16);
    pk.y = (unsigned)f2bf(v.z) | ((unsigned)f2bf(v.w) << 16);
    *(uint2*)(wb + i) = pk;
}

// ---------------------------------------------------------------------------
// k_xt: x fp32 [b][192][16384] -> xT bf16 [b][16384][192]
// ---------------------------------------------------------------------------
__global__ __launch_bounds__(256) void k_xt(const float* __restrict__ x,
                                            ushort_t* __restrict__ xT) {
    __shared__ ushort_t tile[64][200];
    const int t = threadIdx.x;
    const int pix0 = blockIdx.x * 64;
    const int b = blockIdx.y;
    const float* xb = x + (size_t)b * CIN * HWPX;
#pragma unroll 4
    for (int r = 0; r < 48; ++r) {
        int ch = r * 4 + (t >> 6);
        float v = xb[(size_t)ch * HWPX + pix0 + (t & 63)];
        tile[t & 63][ch] = f2bf(v);
    }
    __syncthreads();
    ushort_t* xTb = xT + ((size_t)b * HWPX + pix0) * CIN;
#pragma unroll
    for (int r = 0; r < 6; ++r) {
        int idx = r * 256 + t;
        int row = idx / 24, cc = (idx % 24) * 8;
        uint4 v = *(const uint4*)&tile[row][cc];
        *(uint4*)(xTb + (size_t)row * CIN + cc) = v;
    }
}

// ---------------------------------------------------------------------------
// k_vt: dw v-section bf16 [b][ch][16384] -> vT bf16 [b][16384][192]
// ---------------------------------------------------------------------------
__global__ __launch_bounds__(256) void k_vt(const ushort_t* __restrict__ dwv,
                                            ushort_t* __restrict__ vT) {
    __shared__ ushort_t tile[64][200];
    const int t = threadIdx.x;
    const int pix0 = blockIdx.x * 64;
    const int b = blockIdx.y;
    const ushort_t* vb = dwv + ((size_t)b * C3 + 2 * CIN) * HWPX;
#pragma unroll 4
    for (int r = 0; r < 24; ++r) {
        int ch = r * 8 + (t >> 5);
        int pix = (t & 31) * 2;
        unsigned v = *(const unsigned*)(vb + (size_t)ch * HWPX + pix0 + pix);
        tile[pix][ch] = (ushort_t)v;
        tile[pix + 1][ch] = (ushort_t)(v >> 16);
    }
    __syncthreads();
    ushort_t* vTb = vT + ((size_t)b * HWPX + pix0) * CIN;
#pragma unroll
    for (int r = 0; r < 6; ++r) {
        int idx = r * 256 + t;
        int row = idx / 24, cc = (idx % 24) * 8;
        uint4 v = *(const uint4*)&tile[row][cc];
        *(uint4*)(vTb + (size_t)row * CIN + cc) = v;
    }
}

// ---------------------------------------------------------------------------
// k_gemm: D[pix][o] = sum_k A[pix][k] * B[o][k]   (MFMA bf16)
// ---------------------------------------------------------------------------
template <bool OUT_BF16>
__global__ __launch_bounds__(256) void k_gemm(const ushort_t* __restrict__ A,
                                              const ushort_t* __restrict__ B,
                                              void* __restrict__ C,
                                              long strideA, long strideB, long strideC) {
    __shared__ ushort_t sA[2][256 * 32];
    __shared__ ushort_t sB[2][64 * 32];
    const int t = threadIdx.x;
    const int lane = t & 63, wave = t >> 6;
    const int o0 = blockIdx.x * 64;
    const int pix0 = blockIdx.y * 256;
    const int b = blockIdx.z;
    const ushort_t* Ab = A + (size_t)b * strideA + (size_t)pix0 * CIN;
    const ushort_t* Bb = B + (size_t)b * strideB + (size_t)o0 * CIN;

    f32x4 acc[4][4];
#pragma unroll
    for (int mi = 0; mi < 4; ++mi)
#pragma unroll
        for (int ni = 0; ni < 4; ++ni) acc[mi][ni] = (f32x4){0.f, 0.f, 0.f, 0.f};

    auto stage = [&](int buf, int k0) {
#pragma unroll
        for (int c2 = 0; c2 < 4; ++c2) {
            int e = c2 * 256 + t;
            int row = e >> 2, slot = e & 3;
            int g = (slot + (row >> 1)) & 3;
            const ushort_t* gp = Ab + (size_t)row * CIN + k0 + g * 8;
            ushort_t* lp = &sA[buf][(c2 * 256 + wave * 64) * 8];
            ASYNC_COPY16(gp, lp);
        }
        {
            int row = t >> 2, slot = t & 3;
            int g = (slot + (row >> 1)) & 3;
            const ushort_t* gp = Bb + (size_t)row * CIN + k0 + g * 8;
            ushort_t* lp = &sB[buf][(wave * 64) * 8];
            ASYNC_COPY16(gp, lp);
        }
    };

    stage(0, 0);
#pragma unroll
    for (int ks = 0; ks < 6; ++ks) {
        __syncthreads();
        if (ks < 5) stage((ks + 1) & 1, (ks + 1) * 32);
        const ushort_t* a_ = sA[ks & 1];
        const ushort_t* b_ = sB[ks & 1];
        const int c = lane >> 4;
        bf16x8 af[4], bfr[4];
#pragma unroll
        for (int mi = 0; mi < 4; ++mi) {
            int row = wave * 64 + mi * 16 + (lane & 15);
            int slot = (c - (row >> 1)) & 3;
            af[mi] = *(const bf16x8*)&a_[row * 32 + slot * 8];
        }
#pragma unroll
        for (int ni = 0; ni < 4; ++ni) {
            int row = ni * 16 + (lane & 15);
            int slot = (c - (row >> 1)) & 3;
            bfr[ni] = *(const bf16x8*)&b_[row * 32 + slot * 8];
        }
#pragma unroll
        for (int mi = 0; mi < 4; ++mi)
#pragma unroll
            for (int ni = 0; ni < 4; ++ni)
                acc[mi][ni] = __builtin_amdgcn_mfma_f32_16x16x32_bf16(
                    af[mi], bfr[ni], acc[mi][ni], 0, 0, 0);
    }

    const int ocol = lane & 15;
    const int prow = (lane >> 4) * 4;
#pragma unroll
    for (int mi = 0; mi < 4; ++mi) {
        int pix = pix0 + wave * 64 + mi * 16 + prow;
#pragma unroll
        for (int ni = 0; ni < 4; ++ni) {
            int o = o0 + ni * 16 + ocol;
            f32x4 v = acc[mi][ni];
            if constexpr (OUT_BF16) {
                ushort_t* Cp = (ushort_t*)C + (size_t)b * strideC + (size_t)o * HWPX + pix;
                uint2 pk;
                pk.x = (unsigned)f2bf(v[0]) | ((unsigned)f2bf(v[1]) << 16);
                pk.y = (unsigned)f2bf(v[2]) | ((unsigned)f2bf(v[3]) << 16);
                *(uint2*)Cp = pk;
            } else {
                float* Cp = (float*)C + (size_t)b * strideC + (size_t)o * HWPX + pix;
                *(float4*)Cp = make_float4(v[0], v[1], v[2], v[3]);
            }
        }
    }
}

// ---------------------------------------------------------------------------
// k_dw: depthwise 3x3 SAME + fused per-channel sum of squares.
// Each thread: 8 contiguous pixels/pass, vector ds_read_b32, zero-padded edges.
// ---------------------------------------------------------------------------
__global__ __launch_bounds__(256) void k_dw(const ushort_t* __restrict__ pre,
                                            const float* __restrict__ dww,
                                            ushort_t* __restrict__ dwout,
                                            float* __restrict__ norm2) {
    __shared__ ushort_t tile_raw[HWPX + 8];
    __shared__ float red[256];
    ushort_t* tile = tile_raw + 4;
    const int ch = blockIdx.x, b = blockIdx.y;
    const int t = threadIdx.x;
    const ushort_t* in = pre + ((size_t)b * C3 + ch) * HWPX;
    ushort_t* outp = dwout + ((size_t)b * C3 + ch) * HWPX;
    float w[9];
#pragma unroll
    for (int i = 0; i < 9; ++i) w[i] = dww[ch * 9 + i];
#pragma unroll
    for (int r = 0; r < 8; ++r) {
        int f = t + r * 256;
        *(uint4*)(tile + f * 8) = *(const uint4*)(in + f * 8);
    }
    __syncthreads();
    float ssq = 0.f;
#pragma unroll 2
    for (int r = 0; r < 8; ++r) {
        int p = r * 2048 + t * 8;
        int y = p >> 7, x0 = p & 127;
        float vin[3][12];
#pragma unroll
        for (int ky = 0; ky < 3; ++ky) {
            int yy = y + ky - 1;
            bool ok = (yy >= 0) && (yy <= 127);
            int base = yy * 128 + x0 - 2;
#pragma unroll
            for (int q = 0; q < 6; ++q) {
                unsigned uu = ok ? *(const unsigned*)&tile[base + q * 2] : 0u;
                vin[ky][q * 2] = __uint_as_float(uu << 16);
                vin[ky][q * 2 + 1] = __uint_as_float(uu & 0xffff0000u);
            }
        }
        if (x0 == 0) {
#pragma unroll
            for (int ky = 0; ky < 3; ++ky) { vin[ky][0] = 0.f; vin[ky][1] = 0.f; }
        }
        if (x0 == 120) {
#pragma unroll
            for (int ky = 0; ky < 3; ++ky) { vin[ky][10] = 0.f; vin[ky][11] = 0.f; }
        }
        ushort_t outv[8];
#pragma unroll
        for (int j = 0; j < 8; ++j) {
            float s = 0.f;
#pragma unroll
            for (int ky = 0; ky < 3; ++ky) {
                s = fmaf(w[ky * 3 + 0], vin[ky][j + 1], s);
                s = fmaf(w[ky * 3 + 1], vin[ky][j + 2], s);
                s = fmaf(w[ky * 3 + 2], vin[ky][j + 3], s);
            }
            ssq = fmaf(s, s, ssq);
            outv[j] = f2bf(s);
        }
        uint4 pk;
        pk.x = (unsigned)outv[0] | ((unsigned)outv[1] << 16);
        pk.y = (unsigned)outv[2] | ((unsigned)outv[3] << 16);
        pk.z = (unsigned)outv[4] | ((unsigned)outv[5] << 16);
        pk.w = (unsigned)outv[6] | ((unsigned)outv[7] << 16);
        *(uint4*)(outp + p) = pk;
    }
    red[t] = ssq;
    __syncthreads();
    for (int s2 = 128; s2 > 0; s2 >>= 1) {
        if (t < s2) red[t] += red[t + s2];
        __syncthreads();
    }
    if (t == 0) norm2[b * C3 + ch] = red[0];
}

// ---------------------------------------------------------------------------
// k_gram: MFMA gram partials. grid (chunk=8, h, b), 4 waves x 512 px each.
// q,k planar bf16 (pixel-contiguous == K-contiguous): direct global frags.
// ---------------------------------------------------------------------------
__global__ __launch_bounds__(256) void k_gram(const ushort_t* __restrict__ qkv_dw,
                                              float* __restrict__ gpart) {
    __shared__ float sG[4][DH][DH];
    const int chunk = blockIdx.x, h = blockIdx.y, b = blockIdx.z;
    const int t = threadIdx.x;
    const int lane = t & 63, wave = t >> 6;
    const ushort_t* qb = qkv_dw + ((size_t)b * C3 + h * DH) * HWPX;
    const ushort_t* kb = qkv_dw + ((size_t)b * C3 + CIN + h * DH) * HWPX;
    f32x4 acc[3][3];
#pragma unroll
    for (int i = 0; i < 3; ++i)
#pragma unroll
        for (int j = 0; j < 3; ++j) acc[i][j] = (f32x4){0.f, 0.f, 0.f, 0.f};

    const int rowoff = (lane & 15);
    const int koff = (lane >> 4) * 8;
#pragma unroll 2
    for (int kp = 0; kp < 16; ++kp) {
        int pix0 = chunk * 2048 + wave * 512 + kp * 32;
        bf16x8 af[3], bk[3];
#pragma unroll
        for (int i = 0; i < 3; ++i)
            af[i] = *(const bf16x8*)(qb + (size_t)(i * 16 + rowoff) * HWPX + pix0 + koff);
#pragma unroll
        for (int j = 0; j < 3; ++j)
            bk[j] = *(const bf16x8*)(kb + (size_t)(j * 16 + rowoff) * HWPX + pix0 + koff);
#pragma unroll
        for (int i = 0; i < 3; ++i)
#pragma unroll
            for (int j = 0; j < 3; ++j)
                acc[i][j] = __builtin_amdgcn_mfma_f32_16x16x32_bf16(af[i], bk[j],
                                                                    acc[i][j], 0, 0, 0);
    }
    const int crow = (lane >> 4) * 4;
    const int dcol = lane & 15;
#pragma unroll
    for (int i = 0; i < 3; ++i)
#pragma unroll
        for (int j = 0; j < 3; ++j)
#pragma unroll
            for (int r = 0; r < 4; ++r)
                sG[wave][i * 16 + crow + r][j * 16 + dcol] = acc[i][j][r];
    __syncthreads();
    const float* sGf = &sG[0][0][0];
    float* g = gpart + (((size_t)(b * NHEADS + h)) * 8 + chunk) * (DH * DH);
#pragma unroll
    for (int e = t; e < DH * DH; e += 256)
        g[e] = sGf[e] + sGf[DH * DH + e] + sGf[2 * DH * DH + e] + sGf[3 * DH * DH + e];
}

// ---------------------------------------------------------------------------
// k_attn: reduce partials -> normalize -> softmax -> att fp32 [b][h][48][48]
// ---------------------------------------------------------------------------
__global__ __launch_bounds__(256) void k_attn(const float* __restrict__ gpart,
                                              const float* __restrict__ norm2,
                                              const float* __restrict__ temperature,
                                              float* __restrict__ att) {
    __shared__ float sA[DH][DH + 1];
    const int h = blockIdx.x, b = blockIdx.y;
    const int t = threadIdx.x;
    const float* base = gpart + ((size_t)(b * NHEADS + h) * 8) * (DH * DH);
    for (int e = t; e < DH * DH; e += 256) {
        float s = 0.f;
#pragma unroll
        for (int c8 = 0; c8 < 8; ++c8) s += base[(size_t)c8 * DH * DH + e];
        int c = e / DH, d = e % DH;
        float nq = fmaxf(sqrtf(norm2[b * C3 + h * DH + c]), 1e-12f);
        float nk = fmaxf(sqrtf(norm2[b * C3 + CIN + h * DH + d]), 1e-12f);
        sA[c][d] = s / (nq * nk) * temperature[h];
    }
    __syncthreads();
    if (t < DH) {
        float m = -1e30f;
#pragma unroll
        for (int d = 0; d < DH; ++d) m = fmaxf(m, sA[t][d]);
        float s = 0.f;
        float row[DH];
#pragma unroll
        for (int d = 0; d < DH; ++d) {
            row[d] = expf(sA[t][d] - m);
            s += row[d];
        }
        float inv = 1.f / s;
#pragma unroll
        for (int d = 0; d < DH; ++d) sA[t][d] = row[d] * inv;
    }
    __syncthreads();
    float* ob = att + ((size_t)(b * NHEADS + h)) * DH * DH;
    for (int e = t; e < DH * DH; e += 256) ob[e] = sA[e / DH][e % DH];
}

// ---------------------------------------------------------------------------
// k_mw: Mw[b][o][192] = proj_w @ blockdiag(att), bf16 out. grid (6 otile, b)
// ---------------------------------------------------------------------------
__global__ __launch_bounds__(256) void k_mw(const float* __restrict__ att,
                                            const float* __restrict__ proj_w,
                                            ushort_t* __restrict__ Mw) {
    __shared__ float satt[NHEADS][DH][DH];
    __shared__ float sproj[32][CIN];
    const int o0 = blockIdx.x * 32, b = blockIdx.y;
    const int t = threadIdx.x;
    {
        const float4* src = (const float4*)(att + (size_t)b * NHEADS * DH * DH);
        float4* dst = (float4*)&satt[0][0][0];
        for (int e = t; e < NHEADS * DH * DH / 4; e += 256) dst[e] = src[e];
        const float4* ps = (const float4*)(proj_w + (size_t)o0 * CIN);
        float4* pd = (float4*)&sproj[0][0];
        for (int e = t; e < 32 * CIN / 4; e += 256) pd[e] = ps[e];
    }
    __syncthreads();
    ushort_t* ob = Mw + (size_t)b * CIN * CIN + (size_t)o0 * CIN;
    for (int e = t; e < 32 * CIN; e += 256) {
        int o = e / CIN, dg = e % CIN;
        int h = dg / DH, d = dg % DH;
        float s = 0.f;
#pragma unroll
        for (int c = 0; c < DH; ++c) s = fmaf(sproj[o][h * DH + c], satt[h][c][d], s);
        ob[e] = f2bf(s);
    }
}

extern "C" void kernel_launch(void* const* d_in, const int* in_sizes, int n_in,
                              void* d_out, int out_size, void* d_ws, size_t ws_size,
                              hipStream_t stream) {
    const float* x = (const float*)d_in[0];
    const float* qkv_w = (const float*)d_in[1];
    const float* dw_w = (const float*)d_in[2];
    const float* proj_w = (const float*)d_in[3];
    const float* temperature = (const float*)d_in[4];
    float* out = (float*)d_out;

    char* ws = (char*)d_ws;
    ushort_t* pre = (ushort_t*)ws;
    ushort_t* vT = (ushort_t*)ws;                    // overlays pre (dead by then)
    ushort_t* dwv = (ushort_t*)(ws + 150994944);
    ushort_t* xT = (ushort_t*)(ws + 251658240);      // dead before k_dw clobbers
    ushort_t* wq = (ushort_t*)(ws + 301989888);
    float* norm2 = (float*)(ws + 302211072);
    float* gpart = (float*)(ws + 302229504);
    ushort_t* Mw = (ushort_t*)(ws + 304588800);
    float* attb = (float*)(ws + 305178624);

    const long sA = (long)HWPX * CIN;
    const long sC_pre = (long)C3 * HWPX;
    const long sB_mw = (long)CIN * CIN;
    const long sC_out = (long)CIN * HWPX;

    k_cvtw<<<dim3(108), 256, 0, stream>>>(qkv_w, wq);
    k_xt<<<dim3(256, 8), 256, 0, stream>>>(x, xT);
    k_gemm<true><<<dim3(9, 64, 8), 256, 0, stream>>>(xT, wq, (void*)pre, sA, 0L, sC_pre);
    k_dw<<<dim3(576, 8), 256, 0, stream>>>(pre, dw_w, dwv, norm2);
    k_gram<<<dim3(8, NHEADS, 8), 256, 0, stream>>>(dwv, gpart);
    k_attn<<<dim3(NHEADS, 8), 256, 0, stream>>>(gpart, norm2, temperature, attb);
    k_mw<<<dim3(6, 8), 256, 0, stream>>>(attb, proj_w, Mw);
    k_vt<<<dim3(256, 8), 256, 0, stream>>>(dwv, vT);
    k_gemm<false><<<dim3(3, 64, 8), 256, 0, stream>>>(vT, Mw, (void*)out, sA, sB_mw, sC_out);
}

// Round 4
// 286.069 us; speedup vs baseline: 2.9611x; 1.1471x over previous
//
#include <hip/hip_runtime.h>
#include <hip/hip_bf16.h>

#define CIN 192
#define C3 576
#define HWPX 16384
#define NHEADS 4
#define DH 48

typedef unsigned short ushort_t;
typedef __attribute__((ext_vector_type(8))) short bf16x8;
typedef __attribute__((ext_vector_type(4))) float f32x4;

__device__ __forceinline__ float bf2f(unsigned short u) {
    return __uint_as_float(((unsigned int)u) << 16);
}
__device__ __forceinline__ unsigned short f2bf(float f) {
    unsigned int u = __float_as_uint(f);
    unsigned int r = (u >> 16) & 1u;
    u += 0x7fffu + r;
    return (unsigned short)(u >> 16);
}

#define ASYNC_COPY16(gptr, lptr)                                                   \
    __builtin_amdgcn_global_load_lds(                                              \
        (__attribute__((address_space(1))) void*)(gptr),                           \
        (__attribute__((address_space(3))) void*)(lptr), 16, 0, 0)

// ---------------------------------------------------------------------------
// k_cvtw: qkv_w fp32 [576,192] -> bf16 row-major
// ---------------------------------------------------------------------------
__global__ __launch_bounds__(256) void k_cvtw(const float* __restrict__ w,
                                              ushort_t* __restrict__ wb) {
    int i = (blockIdx.x * 256 + threadIdx.x) * 4;
    float4 v = *(const float4*)(w + i);
    uint2 pk;
    pk.x = (unsigned)f2bf(v.x) | ((unsigned)f2bf(v.y) << 16);
    pk.y = (unsigned)f2bf(v.z) | ((unsigned)f2bf(v.w) << 16);
    *(uint2*)(wb + i) = pk;
}

// ---------------------------------------------------------------------------
// k_xt: x fp32 [b][192][16384] -> xT bf16 [b][16384][192]
// ---------------------------------------------------------------------------
__global__ __launch_bounds__(256) void k_xt(const float* __restrict__ x,
                                            ushort_t* __restrict__ xT) {
    __shared__ ushort_t tile[64][200];
    const int t = threadIdx.x;
    const int pix0 = blockIdx.x * 64;
    const int b = blockIdx.y;
    const float* xb = x + (size_t)b * CIN * HWPX;
#pragma unroll 4
    for (int r = 0; r < 48; ++r) {
        int ch = r * 4 + (t >> 6);
        float v = xb[(size_t)ch * HWPX + pix0 + (t & 63)];
        tile[t & 63][ch] = f2bf(v);
    }
    __syncthreads();
    ushort_t* xTb = xT + ((size_t)b * HWPX + pix0) * CIN;
#pragma unroll
    for (int r = 0; r < 6; ++r) {
        int idx = r * 256 + t;
        int row = idx / 24, cc = (idx % 24) * 8;
        uint4 v = *(const uint4*)&tile[row][cc];
        *(uint4*)(xTb + (size_t)row * CIN + cc) = v;
    }
}

// ---------------------------------------------------------------------------
// k_vt: dw v-section bf16 [b][ch][16384] -> vT bf16 [b][16384][192]
// ---------------------------------------------------------------------------
__global__ __launch_bounds__(256) void k_vt(const ushort_t* __restrict__ dwv,
                                            ushort_t* __restrict__ vT) {
    __shared__ ushort_t tile[64][200];
    const int t = threadIdx.x;
    const int pix0 = blockIdx.x * 64;
    const int b = blockIdx.y;
    const ushort_t* vb = dwv + ((size_t)b * C3 + 2 * CIN) * HWPX;
#pragma unroll 4
    for (int r = 0; r < 24; ++r) {
        int ch = r * 8 + (t >> 5);
        int pix = (t & 31) * 2;
        unsigned v = *(const unsigned*)(vb + (size_t)ch * HWPX + pix0 + pix);
        tile[pix][ch] = (ushort_t)v;
        tile[pix + 1][ch] = (ushort_t)(v >> 16);
    }
    __syncthreads();
    ushort_t* vTb = vT + ((size_t)b * HWPX + pix0) * CIN;
#pragma unroll
    for (int r = 0; r < 6; ++r) {
        int idx = r * 256 + t;
        int row = idx / 24, cc = (idx % 24) * 8;
        uint4 v = *(const uint4*)&tile[row][cc];
        *(uint4*)(vTb + (size_t)row * CIN + cc) = v;
    }
}

// ---------------------------------------------------------------------------
// k_gemm: D[pix][o] = sum_k A[pix][k] * B[o][k]   (MFMA bf16)
// BM=128 pix x BN=192 o, 4 waves (2x2), each wave 64pix x 96o (4x6 frags)
// ---------------------------------------------------------------------------
template <bool OUT_BF16>
__global__ __launch_bounds__(256) void k_gemm(const ushort_t* __restrict__ A,
                                              const ushort_t* __restrict__ B,
                                              void* __restrict__ C,
                                              long strideA, long strideB, long strideC) {
    __shared__ ushort_t sA[2][128 * 32];
    __shared__ ushort_t sB[2][192 * 32];
    const int t = threadIdx.x;
    const int lane = t & 63, wave = t >> 6;
    const int wrow = wave >> 1, wcol = wave & 1;
    const int pix0 = blockIdx.x * 128;
    const int o0 = blockIdx.y * 192;
    const int b = blockIdx.z;
    const ushort_t* Ab = A + (size_t)b * strideA + (size_t)pix0 * CIN;
    const ushort_t* Bb = B + (size_t)b * strideB + (size_t)o0 * CIN;

    f32x4 acc[4][6];
#pragma unroll
    for (int mi = 0; mi < 4; ++mi)
#pragma unroll
        for (int ni = 0; ni < 6; ++ni) acc[mi][ni] = (f32x4){0.f, 0.f, 0.f, 0.f};

    auto stage = [&](int buf, int k0) {
#pragma unroll
        for (int c2 = 0; c2 < 2; ++c2) {
            int e = c2 * 256 + t;
            int row = e >> 2, slot = e & 3;
            int g = (slot + (row >> 1)) & 3;
            const ushort_t* gp = Ab + (size_t)row * CIN + k0 + g * 8;
            ushort_t* lp = &sA[buf][(c2 * 256 + wave * 64) * 8];
            ASYNC_COPY16(gp, lp);
        }
#pragma unroll
        for (int c3 = 0; c3 < 3; ++c3) {
            int e = c3 * 256 + t;
            int row = e >> 2, slot = e & 3;
            int g = (slot + (row >> 1)) & 3;
            const ushort_t* gp = Bb + (size_t)row * CIN + k0 + g * 8;
            ushort_t* lp = &sB[buf][(c3 * 256 + wave * 64) * 8];
            ASYNC_COPY16(gp, lp);
        }
    };

    stage(0, 0);
#pragma unroll
    for (int ks = 0; ks < 6; ++ks) {
        __syncthreads();
        if (ks < 5) stage((ks + 1) & 1, (ks + 1) * 32);
        const ushort_t* a_ = sA[ks & 1];
        const ushort_t* b_ = sB[ks & 1];
        const int c = lane >> 4;
        bf16x8 af[4], bfr[6];
#pragma unroll
        for (int mi = 0; mi < 4; ++mi) {
            int row = wrow * 64 + mi * 16 + (lane & 15);
            int slot = (c - (row >> 1)) & 3;
            af[mi] = *(const bf16x8*)&a_[row * 32 + slot * 8];
        }
#pragma unroll
        for (int ni = 0; ni < 6; ++ni) {
            int row = wcol * 96 + ni * 16 + (lane & 15);
            int slot = (c - (row >> 1)) & 3;
            bfr[ni] = *(const bf16x8*)&b_[row * 32 + slot * 8];
        }
#pragma unroll
        for (int mi = 0; mi < 4; ++mi)
#pragma unroll
            for (int ni = 0; ni < 6; ++ni)
                acc[mi][ni] = __builtin_amdgcn_mfma_f32_16x16x32_bf16(
                    af[mi], bfr[ni], acc[mi][ni], 0, 0, 0);
    }

    const int ocol = lane & 15;
    const int prow = (lane >> 4) * 4;
#pragma unroll
    for (int mi = 0; mi < 4; ++mi) {
        int pix = pix0 + wrow * 64 + mi * 16 + prow;
#pragma unroll
        for (int ni = 0; ni < 6; ++ni) {
            int o = o0 + wcol * 96 + ni * 16 + ocol;
            f32x4 v = acc[mi][ni];
            if constexpr (OUT_BF16) {
                ushort_t* Cp = (ushort_t*)C + (size_t)b * strideC + (size_t)o * HWPX + pix;
                uint2 pk;
                pk.x = (unsigned)f2bf(v[0]) | ((unsigned)f2bf(v[1]) << 16);
                pk.y = (unsigned)f2bf(v[2]) | ((unsigned)f2bf(v[3]) << 16);
                *(uint2*)Cp = pk;
            } else {
                float* Cp = (float*)C + (size_t)b * strideC + (size_t)o * HWPX + pix;
                *(float4*)Cp = make_float4(v[0], v[1], v[2], v[3]);
            }
        }
    }
}

// ---------------------------------------------------------------------------
// k_dw: depthwise 3x3 SAME + fused per-channel sum of squares.
// ---------------------------------------------------------------------------
__global__ __launch_bounds__(256) void k_dw(const ushort_t* __restrict__ pre,
                                            const float* __restrict__ dww,
                                            ushort_t* __restrict__ dwout,
                                            float* __restrict__ norm2) {
    __shared__ ushort_t tile_raw[HWPX + 8];
    __shared__ float red[256];
    ushort_t* tile = tile_raw + 4;
    const int ch = blockIdx.x, b = blockIdx.y;
    const int t = threadIdx.x;
    const ushort_t* in = pre + ((size_t)b * C3 + ch) * HWPX;
    ushort_t* outp = dwout + ((size_t)b * C3 + ch) * HWPX;
    float w[9];
#pragma unroll
    for (int i = 0; i < 9; ++i) w[i] = dww[ch * 9 + i];
#pragma unroll
    for (int r = 0; r < 8; ++r) {
        int f = t + r * 256;
        *(uint4*)(tile + f * 8) = *(const uint4*)(in + f * 8);
    }
    __syncthreads();
    float ssq = 0.f;
#pragma unroll 2
    for (int r = 0; r < 8; ++r) {
        int p = r * 2048 + t * 8;
        int y = p >> 7, x0 = p & 127;
        float vin[3][12];
#pragma unroll
        for (int ky = 0; ky < 3; ++ky) {
            int yy = y + ky - 1;
            bool ok = (yy >= 0) && (yy <= 127);
            int base = yy * 128 + x0 - 2;
#pragma unroll
            for (int q = 0; q < 6; ++q) {
                unsigned uu = ok ? *(const unsigned*)&tile[base + q * 2] : 0u;
                vin[ky][q * 2] = __uint_as_float(uu << 16);
                vin[ky][q * 2 + 1] = __uint_as_float(uu & 0xffff0000u);
            }
        }
        if (x0 == 0) {
#pragma unroll
            for (int ky = 0; ky < 3; ++ky) { vin[ky][0] = 0.f; vin[ky][1] = 0.f; }
        }
        if (x0 == 120) {
#pragma unroll
            for (int ky = 0; ky < 3; ++ky) { vin[ky][10] = 0.f; vin[ky][11] = 0.f; }
        }
        ushort_t outv[8];
#pragma unroll
        for (int j = 0; j < 8; ++j) {
            float s = 0.f;
#pragma unroll
            for (int ky = 0; ky < 3; ++ky) {
                s = fmaf(w[ky * 3 + 0], vin[ky][j + 1], s);
                s = fmaf(w[ky * 3 + 1], vin[ky][j + 2], s);
                s = fmaf(w[ky * 3 + 2], vin[ky][j + 3], s);
            }
            ssq = fmaf(s, s, ssq);
            outv[j] = f2bf(s);
        }
        uint4 pk;
        pk.x = (unsigned)outv[0] | ((unsigned)outv[1] << 16);
        pk.y = (unsigned)outv[2] | ((unsigned)outv[3] << 16);
        pk.z = (unsigned)outv[4] | ((unsigned)outv[5] << 16);
        pk.w = (unsigned)outv[6] | ((unsigned)outv[7] << 16);
        *(uint4*)(outp + p) = pk;
    }
    red[t] = ssq;
    __syncthreads();
    for (int s2 = 128; s2 > 0; s2 >>= 1) {
        if (t < s2) red[t] += red[t + s2];
        __syncthreads();
    }
    if (t == 0) norm2[b * C3 + ch] = red[0];
}

// ---------------------------------------------------------------------------
// k_gram: MFMA gram partials. grid (chunk=8, h, b), 4 waves x 512 px each.
// ---------------------------------------------------------------------------
__global__ __launch_bounds__(256) void k_gram(const ushort_t* __restrict__ qkv_dw,
                                              float* __restrict__ gpart) {
    __shared__ float sG[4][DH][DH];
    const int chunk = blockIdx.x, h = blockIdx.y, b = blockIdx.z;
    const int t = threadIdx.x;
    const int lane = t & 63, wave = t >> 6;
    const ushort_t* qb = qkv_dw + ((size_t)b * C3 + h * DH) * HWPX;
    const ushort_t* kb = qkv_dw + ((size_t)b * C3 + CIN + h * DH) * HWPX;
    f32x4 acc[3][3];
#pragma unroll
    for (int i = 0; i < 3; ++i)
#pragma unroll
        for (int j = 0; j < 3; ++j) acc[i][j] = (f32x4){0.f, 0.f, 0.f, 0.f};

    const int rowoff = (lane & 15);
    const int koff = (lane >> 4) * 8;
#pragma unroll 2
    for (int kp = 0; kp < 16; ++kp) {
        int pix0 = chunk * 2048 + wave * 512 + kp * 32;
        bf16x8 af[3], bk[3];
#pragma unroll
        for (int i = 0; i < 3; ++i)
            af[i] = *(const bf16x8*)(qb + (size_t)(i * 16 + rowoff) * HWPX + pix0 + koff);
#pragma unroll
        for (int j = 0; j < 3; ++j)
            bk[j] = *(const bf16x8*)(kb + (size_t)(j * 16 + rowoff) * HWPX + pix0 + koff);
#pragma unroll
        for (int i = 0; i < 3; ++i)
#pragma unroll
            for (int j = 0; j < 3; ++j)
                acc[i][j] = __builtin_amdgcn_mfma_f32_16x16x32_bf16(af[i], bk[j],
                                                                    acc[i][j], 0, 0, 0);
    }
    const int crow = (lane >> 4) * 4;
    const int dcol = lane & 15;
#pragma unroll
    for (int i = 0; i < 3; ++i)
#pragma unroll
        for (int j = 0; j < 3; ++j)
#pragma unroll
            for (int r = 0; r < 4; ++r)
                sG[wave][i * 16 + crow + r][j * 16 + dcol] = acc[i][j][r];
    __syncthreads();
    const float* sGf = &sG[0][0][0];
    float* g = gpart + (((size_t)(b * NHEADS + h)) * 8 + chunk) * (DH * DH);
#pragma unroll
    for (int e = t; e < DH * DH; e += 256)
        g[e] = sGf[e] + sGf[DH * DH + e] + sGf[2 * DH * DH + e] + sGf[3 * DH * DH + e];
}

// ---------------------------------------------------------------------------
// k_attn: reduce partials -> normalize -> softmax -> att fp32 [b][h][48][48]
// ---------------------------------------------------------------------------
__global__ __launch_bounds__(256) void k_attn(const float* __restrict__ gpart,
                                              const float* __restrict__ norm2,
                                              const float* __restrict__ temperature,
                                              float* __restrict__ att) {
    __shared__ float sA[DH][DH + 1];
    const int h = blockIdx.x, b = blockIdx.y;
    const int t = threadIdx.x;
    const float* base = gpart + ((size_t)(b * NHEADS + h) * 8) * (DH * DH);
    for (int e = t; e < DH * DH; e += 256) {
        float s = 0.f;
#pragma unroll
        for (int c8 = 0; c8 < 8; ++c8) s += base[(size_t)c8 * DH * DH + e];
        int c = e / DH, d = e % DH;
        float nq = fmaxf(sqrtf(norm2[b * C3 + h * DH + c]), 1e-12f);
        float nk = fmaxf(sqrtf(norm2[b * C3 + CIN + h * DH + d]), 1e-12f);
        sA[c][d] = s / (nq * nk) * temperature[h];
    }
    __syncthreads();
    if (t < DH) {
        float m = -1e30f;
#pragma unroll
        for (int d = 0; d < DH; ++d) m = fmaxf(m, sA[t][d]);
        float s = 0.f;
        float row[DH];
#pragma unroll
        for (int d = 0; d < DH; ++d) {
            row[d] = expf(sA[t][d] - m);
            s += row[d];
        }
        float inv = 1.f / s;
#pragma unroll
        for (int d = 0; d < DH; ++d) sA[t][d] = row[d] * inv;
    }
    __syncthreads();
    float* ob = att + ((size_t)(b * NHEADS + h)) * DH * DH;
    for (int e = t; e < DH * DH; e += 256) ob[e] = sA[e / DH][e % DH];
}

// ---------------------------------------------------------------------------
// k_mw: Mw[b][o][192] = proj_w @ blockdiag(att), bf16 out. grid (6 otile, b)
// ---------------------------------------------------------------------------
__global__ __launch_bounds__(256) void k_mw(const float* __restrict__ att,
                                            const float* __restrict__ proj_w,
                                            ushort_t* __restrict__ Mw) {
    __shared__ float satt[NHEADS][DH][DH];
    __shared__ float sproj[32][CIN];
    const int o0 = blockIdx.x * 32, b = blockIdx.y;
    const int t = threadIdx.x;
    {
        const float4* src = (const float4*)(att + (size_t)b * NHEADS * DH * DH);
        float4* dst = (float4*)&satt[0][0][0];
        for (int e = t; e < NHEADS * DH * DH / 4; e += 256) dst[e] = src[e];
        const float4* ps = (const float4*)(proj_w + (size_t)o0 * CIN);
        float4* pd = (float4*)&sproj[0][0];
        for (int e = t; e < 32 * CIN / 4; e += 256) pd[e] = ps[e];
    }
    __syncthreads();
    ushort_t* ob = Mw + (size_t)b * CIN * CIN + (size_t)o0 * CIN;
    for (int e = t; e < 32 * CIN; e += 256) {
        int o = e / CIN, dg = e % CIN;
        int h = dg / DH, d = dg % DH;
        float s = 0.f;
#pragma unroll
        for (int c = 0; c < DH; ++c) s = fmaf(sproj[o][h * DH + c], satt[h][c][d], s);
        ob[e] = f2bf(s);
    }
}

extern "C" void kernel_launch(void* const* d_in, const int* in_sizes, int n_in,
                              void* d_out, int out_size, void* d_ws, size_t ws_size,
                              hipStream_t stream) {
    const float* x = (const float*)d_in[0];
    const float* qkv_w = (const float*)d_in[1];
    const float* dw_w = (const float*)d_in[2];
    const float* proj_w = (const float*)d_in[3];
    const float* temperature = (const float*)d_in[4];
    float* out = (float*)d_out;

    char* ws = (char*)d_ws;
    ushort_t* pre = (ushort_t*)ws;
    ushort_t* vT = (ushort_t*)ws;                    // overlays pre (dead by then)
    ushort_t* dwv = (ushort_t*)(ws + 150994944);
    ushort_t* xT = (ushort_t*)(ws + 251658240);      // dead before k_dw clobbers
    ushort_t* wq = (ushort_t*)(ws + 301989888);
    float* norm2 = (float*)(ws + 302211072);
    float* gpart = (float*)(ws + 302229504);
    ushort_t* Mw = (ushort_t*)(ws + 304588800);
    float* attb = (float*)(ws + 305178624);

    const long sA = (long)HWPX * CIN;
    const long sC_pre = (long)C3 * HWPX;
    const long sB_mw = (long)CIN * CIN;
    const long sC_out = (long)CIN * HWPX;

    k_cvtw<<<dim3(108), 256, 0, stream>>>(qkv_w, wq);
    k_xt<<<dim3(256, 8), 256, 0, stream>>>(x, xT);
    k_gemm<true><<<dim3(128, 3, 8), 256, 0, stream>>>(xT, wq, (void*)pre, sA, 0L, sC_pre);
    k_dw<<<dim3(576, 8), 256, 0, stream>>>(pre, dw_w, dwv, norm2);
    k_gram<<<dim3(8, NHEADS, 8), 256, 0, stream>>>(dwv, gpart);
    k_attn<<<dim3(NHEADS, 8), 256, 0, stream>>>(gpart, norm2, temperature, attb);
    k_mw<<<dim3(6, 8), 256, 0, stream>>>(attb, proj_w, Mw);
    k_vt<<<dim3(256, 8), 256, 0, stream>>>(dwv, vT);
    k_gemm<false><<<dim3(128, 1, 8), 256, 0, stream>>>(vT, Mw, (void*)out, sA, sB_mw, sC_out);
}

// Round 5
// 274.710 us; speedup vs baseline: 3.0836x; 1.0413x over previous
//
#include <hip/hip_runtime.h>
#include <hip/hip_bf16.h>

#define CIN 192
#define C3 576
#define HWPX 16384
#define NHEADS 4
#define DH 48

typedef unsigned short ushort_t;
typedef __attribute__((ext_vector_type(8))) short bf16x8;
typedef __attribute__((ext_vector_type(4))) float f32x4;

__device__ __forceinline__ float bf2f(unsigned short u) {
    return __uint_as_float(((unsigned int)u) << 16);
}
__device__ __forceinline__ unsigned short f2bf(float f) {
    unsigned int u = __float_as_uint(f);
    unsigned int r = (u >> 16) & 1u;
    u += 0x7fffu + r;
    return (unsigned short)(u >> 16);
}

#define ASYNC_COPY16(gptr, lptr)                                                   \
    __builtin_amdgcn_global_load_lds(                                              \
        (__attribute__((address_space(1))) void*)(gptr),                           \
        (__attribute__((address_space(3))) void*)(lptr), 16, 0, 0)

// ---------------------------------------------------------------------------
// k_cvtw: qkv_w fp32 [576,192] -> bf16 row-major
// ---------------------------------------------------------------------------
__global__ __launch_bounds__(256) void k_cvtw(const float* __restrict__ w,
                                              ushort_t* __restrict__ wb) {
    int i = (blockIdx.x * 256 + threadIdx.x) * 4;
    float4 v = *(const float4*)(w + i);
    uint2 pk;
    pk.x = (unsigned)f2bf(v.x) | ((unsigned)f2bf(v.y) << 16);
    pk.y = (unsigned)f2bf(v.z) | ((unsigned)f2bf(v.w) << 16);
    *(uint2*)(wb + i) = pk;
}

// ---------------------------------------------------------------------------
// k_xt: x fp32 [b][192][16384] -> xT bf16 [b][16384][192]
// ---------------------------------------------------------------------------
__global__ __launch_bounds__(256) void k_xt(const float* __restrict__ x,
                                            ushort_t* __restrict__ xT) {
    __shared__ ushort_t tile[64][200];
    const int t = threadIdx.x;
    const int pix0 = blockIdx.x * 64;
    const int b = blockIdx.y;
    const float* xb = x + (size_t)b * CIN * HWPX;
#pragma unroll 4
    for (int r = 0; r < 48; ++r) {
        int ch = r * 4 + (t >> 6);
        float v = xb[(size_t)ch * HWPX + pix0 + (t & 63)];
        tile[t & 63][ch] = f2bf(v);
    }
    __syncthreads();
    ushort_t* xTb = xT + ((size_t)b * HWPX + pix0) * CIN;
#pragma unroll
    for (int r = 0; r < 6; ++r) {
        int idx = r * 256 + t;
        int row = idx / 24, cc = (idx % 24) * 8;
        uint4 v = *(const uint4*)&tile[row][cc];
        *(uint4*)(xTb + (size_t)row * CIN + cc) = v;
    }
}

// ---------------------------------------------------------------------------
// k_vt: dw v-section bf16 [b][ch][16384] -> vT bf16 [b][16384][192]
// ---------------------------------------------------------------------------
__global__ __launch_bounds__(256) void k_vt(const ushort_t* __restrict__ dwv,
                                            ushort_t* __restrict__ vT) {
    __shared__ ushort_t tile[64][200];
    const int t = threadIdx.x;
    const int pix0 = blockIdx.x * 64;
    const int b = blockIdx.y;
    const ushort_t* vb = dwv + ((size_t)b * C3 + 2 * CIN) * HWPX;
#pragma unroll 4
    for (int r = 0; r < 24; ++r) {
        int ch = r * 8 + (t >> 5);
        int pix = (t & 31) * 2;
        unsigned v = *(const unsigned*)(vb + (size_t)ch * HWPX + pix0 + pix);
        tile[pix][ch] = (ushort_t)v;
        tile[pix + 1][ch] = (ushort_t)(v >> 16);
    }
    __syncthreads();
    ushort_t* vTb = vT + ((size_t)b * HWPX + pix0) * CIN;
#pragma unroll
    for (int r = 0; r < 6; ++r) {
        int idx = r * 256 + t;
        int row = idx / 24, cc = (idx % 24) * 8;
        uint4 v = *(const uint4*)&tile[row][cc];
        *(uint4*)(vTb + (size_t)row * CIN + cc) = v;
    }
}

// ---------------------------------------------------------------------------
// k_gemm: D[pix][o] = sum_k A[pix][k] * B[o][k]   (MFMA bf16)
// BM=128 pix x BN=192 o, 512 threads / 8 waves (4x2), each wave 32pix x 96o
// (2x6 frags, 48 acc VGPR/lane) -> ~2x occupancy vs 4-wave version
// ---------------------------------------------------------------------------
template <bool OUT_BF16>
__global__ __launch_bounds__(512) void k_gemm(const ushort_t* __restrict__ A,
                                              const ushort_t* __restrict__ B,
                                              void* __restrict__ C,
                                              long strideA, long strideB, long strideC) {
    __shared__ ushort_t sA[2][128 * 32];
    __shared__ ushort_t sB[2][192 * 32];
    const int t = threadIdx.x;
    const int lane = t & 63, wave = t >> 6;
    const int wrow = wave >> 1, wcol = wave & 1;
    const int pix0 = blockIdx.x * 128;
    const int o0 = blockIdx.y * 192;
    const int b = blockIdx.z;
    const ushort_t* Ab = A + (size_t)b * strideA + (size_t)pix0 * CIN;
    const ushort_t* Bb = B + (size_t)b * strideB + (size_t)o0 * CIN;

    f32x4 acc[2][6];
#pragma unroll
    for (int mi = 0; mi < 2; ++mi)
#pragma unroll
        for (int ni = 0; ni < 6; ++ni) acc[mi][ni] = (f32x4){0.f, 0.f, 0.f, 0.f};

    auto stage = [&](int buf, int k0) {
        {
            // A: 128 rows x 4 slots = 512 transfers, 1 per thread
            int row = t >> 2, slot = t & 3;
            int g = (slot + (row >> 1)) & 3;
            const ushort_t* gp = Ab + (size_t)row * CIN + k0 + g * 8;
            ushort_t* lp = &sA[buf][(wave * 64) * 8];
            ASYNC_COPY16(gp, lp);
        }
        {
            // B rows 0..127: 512 transfers
            int row = t >> 2, slot = t & 3;
            int g = (slot + (row >> 1)) & 3;
            const ushort_t* gp = Bb + (size_t)row * CIN + k0 + g * 8;
            ushort_t* lp = &sB[buf][(wave * 64) * 8];
            ASYNC_COPY16(gp, lp);
        }
        if (t < 256) {
            // B rows 128..191: 256 transfers, waves 0..3
            int e = 512 + t;
            int row = e >> 2, slot = e & 3;
            int g = (slot + (row >> 1)) & 3;
            const ushort_t* gp = Bb + (size_t)row * CIN + k0 + g * 8;
            ushort_t* lp = &sB[buf][(512 + wave * 64) * 8];
            ASYNC_COPY16(gp, lp);
        }
    };

    stage(0, 0);
#pragma unroll
    for (int ks = 0; ks < 6; ++ks) {
        __syncthreads();
        if (ks < 5) stage((ks + 1) & 1, (ks + 1) * 32);
        const ushort_t* a_ = sA[ks & 1];
        const ushort_t* b_ = sB[ks & 1];
        const int c = lane >> 4;
        bf16x8 af[2], bfr[6];
#pragma unroll
        for (int mi = 0; mi < 2; ++mi) {
            int row = wrow * 32 + mi * 16 + (lane & 15);
            int slot = (c - (row >> 1)) & 3;
            af[mi] = *(const bf16x8*)&a_[row * 32 + slot * 8];
        }
#pragma unroll
        for (int ni = 0; ni < 6; ++ni) {
            int row = wcol * 96 + ni * 16 + (lane & 15);
            int slot = (c - (row >> 1)) & 3;
            bfr[ni] = *(const bf16x8*)&b_[row * 32 + slot * 8];
        }
#pragma unroll
        for (int mi = 0; mi < 2; ++mi)
#pragma unroll
            for (int ni = 0; ni < 6; ++ni)
                acc[mi][ni] = __builtin_amdgcn_mfma_f32_16x16x32_bf16(
                    af[mi], bfr[ni], acc[mi][ni], 0, 0, 0);
    }

    const int ocol = lane & 15;
    const int prow = (lane >> 4) * 4;
#pragma unroll
    for (int mi = 0; mi < 2; ++mi) {
        int pix = pix0 + wrow * 32 + mi * 16 + prow;
#pragma unroll
        for (int ni = 0; ni < 6; ++ni) {
            int o = o0 + wcol * 96 + ni * 16 + ocol;
            f32x4 v = acc[mi][ni];
            if constexpr (OUT_BF16) {
                ushort_t* Cp = (ushort_t*)C + (size_t)b * strideC + (size_t)o * HWPX + pix;
                uint2 pk;
                pk.x = (unsigned)f2bf(v[0]) | ((unsigned)f2bf(v[1]) << 16);
                pk.y = (unsigned)f2bf(v[2]) | ((unsigned)f2bf(v[3]) << 16);
                *(uint2*)Cp = pk;
            } else {
                float* Cp = (float*)C + (size_t)b * strideC + (size_t)o * HWPX + pix;
                *(float4*)Cp = make_float4(v[0], v[1], v[2], v[3]);
            }
        }
    }
}

// ---------------------------------------------------------------------------
// k_dw: depthwise 3x3 SAME + fused per-channel sum of squares.
// ---------------------------------------------------------------------------
__global__ __launch_bounds__(256) void k_dw(const ushort_t* __restrict__ pre,
                                            const float* __restrict__ dww,
                                            ushort_t* __restrict__ dwout,
                                            float* __restrict__ norm2) {
    __shared__ ushort_t tile_raw[HWPX + 8];
    __shared__ float red[256];
    ushort_t* tile = tile_raw + 4;
    const int ch = blockIdx.x, b = blockIdx.y;
    const int t = threadIdx.x;
    const ushort_t* in = pre + ((size_t)b * C3 + ch) * HWPX;
    ushort_t* outp = dwout + ((size_t)b * C3 + ch) * HWPX;
    float w[9];
#pragma unroll
    for (int i = 0; i < 9; ++i) w[i] = dww[ch * 9 + i];
#pragma unroll
    for (int r = 0; r < 8; ++r) {
        int f = t + r * 256;
        *(uint4*)(tile + f * 8) = *(const uint4*)(in + f * 8);
    }
    __syncthreads();
    float ssq = 0.f;
#pragma unroll 2
    for (int r = 0; r < 8; ++r) {
        int p = r * 2048 + t * 8;
        int y = p >> 7, x0 = p & 127;
        float vin[3][12];
#pragma unroll
        for (int ky = 0; ky < 3; ++ky) {
            int yy = y + ky - 1;
            bool ok = (yy >= 0) && (yy <= 127);
            int base = yy * 128 + x0 - 2;
#pragma unroll
            for (int q = 0; q < 6; ++q) {
                unsigned uu = ok ? *(const unsigned*)&tile[base + q * 2] : 0u;
                vin[ky][q * 2] = __uint_as_float(uu << 16);
                vin[ky][q * 2 + 1] = __uint_as_float(uu & 0xffff0000u);
            }
        }
        if (x0 == 0) {
#pragma unroll
            for (int ky = 0; ky < 3; ++ky) { vin[ky][0] = 0.f; vin[ky][1] = 0.f; }
        }
        if (x0 == 120) {
#pragma unroll
            for (int ky = 0; ky < 3; ++ky) { vin[ky][10] = 0.f; vin[ky][11] = 0.f; }
        }
        ushort_t outv[8];
#pragma unroll
        for (int j = 0; j < 8; ++j) {
            float s = 0.f;
#pragma unroll
            for (int ky = 0; ky < 3; ++ky) {
                s = fmaf(w[ky * 3 + 0], vin[ky][j + 1], s);
                s = fmaf(w[ky * 3 + 1], vin[ky][j + 2], s);
                s = fmaf(w[ky * 3 + 2], vin[ky][j + 3], s);
            }
            ssq = fmaf(s, s, ssq);
            outv[j] = f2bf(s);
        }
        uint4 pk;
        pk.x = (unsigned)outv[0] | ((unsigned)outv[1] << 16);
        pk.y = (unsigned)outv[2] | ((unsigned)outv[3] << 16);
        pk.z = (unsigned)outv[4] | ((unsigned)outv[5] << 16);
        pk.w = (unsigned)outv[6] | ((unsigned)outv[7] << 16);
        *(uint4*)(outp + p) = pk;
    }
    red[t] = ssq;
    __syncthreads();
    for (int s2 = 128; s2 > 0; s2 >>= 1) {
        if (t < s2) red[t] += red[t + s2];
        __syncthreads();
    }
    if (t == 0) norm2[b * C3 + ch] = red[0];
}

// ---------------------------------------------------------------------------
// k_gram: MFMA gram partials. grid (chunk=8, h, b), 4 waves x 512 px each.
// ---------------------------------------------------------------------------
__global__ __launch_bounds__(256) void k_gram(const ushort_t* __restrict__ qkv_dw,
                                              float* __restrict__ gpart) {
    __shared__ float sG[4][DH][DH];
    const int chunk = blockIdx.x, h = blockIdx.y, b = blockIdx.z;
    const int t = threadIdx.x;
    const int lane = t & 63, wave = t >> 6;
    const ushort_t* qb = qkv_dw + ((size_t)b * C3 + h * DH) * HWPX;
    const ushort_t* kb = qkv_dw + ((size_t)b * C3 + CIN + h * DH) * HWPX;
    f32x4 acc[3][3];
#pragma unroll
    for (int i = 0; i < 3; ++i)
#pragma unroll
        for (int j = 0; j < 3; ++j) acc[i][j] = (f32x4){0.f, 0.f, 0.f, 0.f};

    const int rowoff = (lane & 15);
    const int koff = (lane >> 4) * 8;
#pragma unroll 2
    for (int kp = 0; kp < 16; ++kp) {
        int pix0 = chunk * 2048 + wave * 512 + kp * 32;
        bf16x8 af[3], bk[3];
#pragma unroll
        for (int i = 0; i < 3; ++i)
            af[i] = *(const bf16x8*)(qb + (size_t)(i * 16 + rowoff) * HWPX + pix0 + koff);
#pragma unroll
        for (int j = 0; j < 3; ++j)
            bk[j] = *(const bf16x8*)(kb + (size_t)(j * 16 + rowoff) * HWPX + pix0 + koff);
#pragma unroll
        for (int i = 0; i < 3; ++i)
#pragma unroll
            for (int j = 0; j < 3; ++j)
                acc[i][j] = __builtin_amdgcn_mfma_f32_16x16x32_bf16(af[i], bk[j],
                                                                    acc[i][j], 0, 0, 0);
    }
    const int crow = (lane >> 4) * 4;
    const int dcol = lane & 15;
#pragma unroll
    for (int i = 0; i < 3; ++i)
#pragma unroll
        for (int j = 0; j < 3; ++j)
#pragma unroll
            for (int r = 0; r < 4; ++r)
                sG[wave][i * 16 + crow + r][j * 16 + dcol] = acc[i][j][r];
    __syncthreads();
    const float* sGf = &sG[0][0][0];
    float* g = gpart + (((size_t)(b * NHEADS + h)) * 8 + chunk) * (DH * DH);
#pragma unroll
    for (int e = t; e < DH * DH; e += 256)
        g[e] = sGf[e] + sGf[DH * DH + e] + sGf[2 * DH * DH + e] + sGf[3 * DH * DH + e];
}

// ---------------------------------------------------------------------------
// k_attn: reduce partials -> normalize -> softmax -> att fp32 [b][h][48][48]
// ---------------------------------------------------------------------------
__global__ __launch_bounds__(256) void k_attn(const float* __restrict__ gpart,
                                              const float* __restrict__ norm2,
                                              const float* __restrict__ temperature,
                                              float* __restrict__ att) {
    __shared__ float sA[DH][DH + 1];
    const int h = blockIdx.x, b = blockIdx.y;
    const int t = threadIdx.x;
    const float* base = gpart + ((size_t)(b * NHEADS + h) * 8) * (DH * DH);
    for (int e = t; e < DH * DH; e += 256) {
        float s = 0.f;
#pragma unroll
        for (int c8 = 0; c8 < 8; ++c8) s += base[(size_t)c8 * DH * DH + e];
        int c = e / DH, d = e % DH;
        float nq = fmaxf(sqrtf(norm2[b * C3 + h * DH + c]), 1e-12f);
        float nk = fmaxf(sqrtf(norm2[b * C3 + CIN + h * DH + d]), 1e-12f);
        sA[c][d] = s / (nq * nk) * temperature[h];
    }
    __syncthreads();
    if (t < DH) {
        float m = -1e30f;
#pragma unroll
        for (int d = 0; d < DH; ++d) m = fmaxf(m, sA[t][d]);
        float s = 0.f;
        float row[DH];
#pragma unroll
        for (int d = 0; d < DH; ++d) {
            row[d] = expf(sA[t][d] - m);
            s += row[d];
        }
        float inv = 1.f / s;
#pragma unroll
        for (int d = 0; d < DH; ++d) sA[t][d] = row[d] * inv;
    }
    __syncthreads();
    float* ob = att + ((size_t)(b * NHEADS + h)) * DH * DH;
    for (int e = t; e < DH * DH; e += 256) ob[e] = sA[e / DH][e % DH];
}

// ---------------------------------------------------------------------------
// k_mw: Mw[b][o][192] = proj_w @ blockdiag(att), bf16 out. grid (6 otile, b)
// ---------------------------------------------------------------------------
__global__ __launch_bounds__(256) void k_mw(const float* __restrict__ att,
                                            const float* __restrict__ proj_w,
                                            ushort_t* __restrict__ Mw) {
    __shared__ float satt[NHEADS][DH][DH];
    __shared__ float sproj[32][CIN];
    const int o0 = blockIdx.x * 32, b = blockIdx.y;
    const int t = threadIdx.x;
    {
        const float4* src = (const float4*)(att + (size_t)b * NHEADS * DH * DH);
        float4* dst = (float4*)&satt[0][0][0];
        for (int e = t; e < NHEADS * DH * DH / 4; e += 256) dst[e] = src[e];
        const float4* ps = (const float4*)(proj_w + (size_t)o0 * CIN);
        float4* pd = (float4*)&sproj[0][0];
        for (int e = t; e < 32 * CIN / 4; e += 256) pd[e] = ps[e];
    }
    __syncthreads();
    ushort_t* ob = Mw + (size_t)b * CIN * CIN + (size_t)o0 * CIN;
    for (int e = t; e < 32 * CIN; e += 256) {
        int o = e / CIN, dg = e % CIN;
        int h = dg / DH, d = dg % DH;
        float s = 0.f;
#pragma unroll
        for (int c = 0; c < DH; ++c) s = fmaf(sproj[o][h * DH + c], satt[h][c][d], s);
        ob[e] = f2bf(s);
    }
}

extern "C" void kernel_launch(void* const* d_in, const int* in_sizes, int n_in,
                              void* d_out, int out_size, void* d_ws, size_t ws_size,
                              hipStream_t stream) {
    const float* x = (const float*)d_in[0];
    const float* qkv_w = (const float*)d_in[1];
    const float* dw_w = (const float*)d_in[2];
    const float* proj_w = (const float*)d_in[3];
    const float* temperature = (const float*)d_in[4];
    float* out = (float*)d_out;

    char* ws = (char*)d_ws;
    ushort_t* pre = (ushort_t*)ws;
    ushort_t* vT = (ushort_t*)ws;                    // overlays pre (dead by then)
    ushort_t* dwv = (ushort_t*)(ws + 150994944);
    ushort_t* xT = (ushort_t*)(ws + 251658240);      // dead before k_dw clobbers
    ushort_t* wq = (ushort_t*)(ws + 301989888);
    float* norm2 = (float*)(ws + 302211072);
    float* gpart = (float*)(ws + 302229504);
    ushort_t* Mw = (ushort_t*)(ws + 304588800);
    float* attb = (float*)(ws + 305178624);

    const long sA = (long)HWPX * CIN;
    const long sC_pre = (long)C3 * HWPX;
    const long sB_mw = (long)CIN * CIN;
    const long sC_out = (long)CIN * HWPX;

    k_cvtw<<<dim3(108), 256, 0, stream>>>(qkv_w, wq);
    k_xt<<<dim3(256, 8), 256, 0, stream>>>(x, xT);
    k_gemm<true><<<dim3(128, 3, 8), 512, 0, stream>>>(xT, wq, (void*)pre, sA, 0L, sC_pre);
    k_dw<<<dim3(576, 8), 256, 0, stream>>>(pre, dw_w, dwv, norm2);
    k_gram<<<dim3(8, NHEADS, 8), 256, 0, stream>>>(dwv, gpart);
    k_attn<<<dim3(NHEADS, 8), 256, 0, stream>>>(gpart, norm2, temperature, attb);
    k_mw<<<dim3(6, 8), 256, 0, stream>>>(attb, proj_w, Mw);
    k_vt<<<dim3(256, 8), 256, 0, stream>>>(dwv, vT);
    k_gemm<false><<<dim3(128, 1, 8), 512, 0, stream>>>(vT, Mw, (void*)out, sA, sB_mw, sC_out);
}

// Round 6
// 253.046 us; speedup vs baseline: 3.3476x; 1.0856x over previous
//
#include <hip/hip_runtime.h>
#include <hip/hip_bf16.h>

#define CIN 192
#define C3 576
#define HWPX 16384
#define NHEADS 4
#define DH 48

typedef unsigned short ushort_t;
typedef __attribute__((ext_vector_type(8))) short bf16x8;
typedef __attribute__((ext_vector_type(4))) float f32x4;

__device__ __forceinline__ float bf2f(unsigned short u) {
    return __uint_as_float(((unsigned int)u) << 16);
}
__device__ __forceinline__ unsigned short f2bf(float f) {
    unsigned int u = __float_as_uint(f);
    unsigned int r = (u >> 16) & 1u;
    u += 0x7fffu + r;
    return (unsigned short)(u >> 16);
}

#define ASYNC_COPY16(gptr, lptr)                                                   \
    __builtin_amdgcn_global_load_lds(                                              \
        (__attribute__((address_space(1))) void*)(gptr),                           \
        (__attribute__((address_space(3))) void*)(lptr), 16, 0, 0)

// ---------------------------------------------------------------------------
// k_cvtw: qkv_w fp32 [576,192] -> bf16 row-major
// ---------------------------------------------------------------------------
__global__ __launch_bounds__(256) void k_cvtw(const float* __restrict__ w,
                                              ushort_t* __restrict__ wb) {
    int i = (blockIdx.x * 256 + threadIdx.x) * 4;
    float4 v = *(const float4*)(w + i);
    uint2 pk;
    pk.x = (unsigned)f2bf(v.x) | ((unsigned)f2bf(v.y) << 16);
    pk.y = (unsigned)f2bf(v.z) | ((unsigned)f2bf(v.w) << 16);
    *(uint2*)(wb + i) = pk;
}

// ---------------------------------------------------------------------------
// k_gemm: D[pix][o] = sum_k A[pix][k] * B[o][k]   (MFMA bf16)
// BM=128 pix x BN=192 o, 512 thr / 8 waves (4x2), wave = 32pix x 96o (2x6).
// A is PLANAR [ch][pix] (fp32 x, or bf16 dw-v): reg-staged transpose into
// sA[pix][32ch] with slot-swizzle (chunk+(row>>1)+(row>>3))&3.
// B row-major k-contig via global_load_lds with (slot+(row>>1))&3 swizzle.
// ---------------------------------------------------------------------------
template <bool A_F32, bool OUT_BF16>
__global__ __launch_bounds__(512) void k_gemm(const void* __restrict__ A,
                                              const ushort_t* __restrict__ B,
                                              void* __restrict__ C,
                                              long strideA, long strideB, long strideC) {
    __shared__ ushort_t sA[2][128 * 32];
    __shared__ ushort_t sB[2][192 * 32];
    const int t = threadIdx.x;
    const int lane = t & 63, wave = t >> 6;
    const int wrow = wave >> 1, wcol = wave & 1;
    const int pix0 = blockIdx.x * 128;
    const int o0 = blockIdx.y * 192;
    const int b = blockIdx.z;
    const ushort_t* Bb = B + (size_t)b * strideB + (size_t)o0 * CIN;

    const int cc = t >> 4;  // channel-in-tile 0..31
    const int jj = t & 15;  // pixel-octet 0..15

    ushort_t av[8];

    auto loadA = [&](int kc) {
        if constexpr (A_F32) {
            const float* Ab = (const float*)A + (size_t)b * strideA +
                              (size_t)(kc + cc) * HWPX + pix0 + jj * 8;
            float4 a0 = *(const float4*)Ab;
            float4 a1 = *(const float4*)(Ab + 4);
            av[0] = f2bf(a0.x); av[1] = f2bf(a0.y);
            av[2] = f2bf(a0.z); av[3] = f2bf(a0.w);
            av[4] = f2bf(a1.x); av[5] = f2bf(a1.y);
            av[6] = f2bf(a1.z); av[7] = f2bf(a1.w);
        } else {
            const ushort_t* Ab = (const ushort_t*)A + (size_t)b * strideA +
                                 (size_t)(kc + cc) * HWPX + pix0 + jj * 8;
            uint4 a = *(const uint4*)Ab;
            av[0] = (ushort_t)a.x; av[1] = (ushort_t)(a.x >> 16);
            av[2] = (ushort_t)a.y; av[3] = (ushort_t)(a.y >> 16);
            av[4] = (ushort_t)a.z; av[5] = (ushort_t)(a.z >> 16);
            av[6] = (ushort_t)a.w; av[7] = (ushort_t)(a.w >> 16);
        }
    };
    auto writeA = [&](int buf) {
        ushort_t* s = sA[buf];
#pragma unroll
        for (int i = 0; i < 8; ++i) {
            int row = jj * 8 + i;
            int slot = ((cc >> 3) + (row >> 1) + (row >> 3)) & 3;
            s[row * 32 + slot * 8 + (cc & 7)] = av[i];
        }
    };
    auto stageB = [&](int buf, int kc) {
        {
            int row = t >> 2, slot = t & 3;
            int g = (slot + (row >> 1)) & 3;
            const ushort_t* gp = Bb + (size_t)row * CIN + kc + g * 8;
            ushort_t* lp = &sB[buf][(wave * 64) * 8];
            ASYNC_COPY16(gp, lp);
        }
        if (t < 256) {
            int e = 512 + t;
            int row = e >> 2, slot = e & 3;
            int g = (slot + (row >> 1)) & 3;
            const ushort_t* gp = Bb + (size_t)row * CIN + kc + g * 8;
            ushort_t* lp = &sB[buf][(512 + wave * 64) * 8];
            ASYNC_COPY16(gp, lp);
        }
    };

    f32x4 acc[2][6];
#pragma unroll
    for (int mi = 0; mi < 2; ++mi)
#pragma unroll
        for (int ni = 0; ni < 6; ++ni) acc[mi][ni] = (f32x4){0.f, 0.f, 0.f, 0.f};

    loadA(0);
    writeA(0);
    stageB(0, 0);
#pragma unroll
    for (int ks = 0; ks < 6; ++ks) {
        __syncthreads();
        const int buf = ks & 1;
        if (ks < 5) {
            loadA((ks + 1) * 32);
            stageB(buf ^ 1, (ks + 1) * 32);
        }
        const ushort_t* a_ = sA[buf];
        const ushort_t* b_ = sB[buf];
        const int c = lane >> 4;
        bf16x8 af[2], bfr[6];
#pragma unroll
        for (int mi = 0; mi < 2; ++mi) {
            int row = wrow * 32 + mi * 16 + (lane & 15);
            int slot = (c + (row >> 1) + (row >> 3)) & 3;
            af[mi] = *(const bf16x8*)&a_[row * 32 + slot * 8];
        }
#pragma unroll
        for (int ni = 0; ni < 6; ++ni) {
            int row = wcol * 96 + ni * 16 + (lane & 15);
            int slot = (c - (row >> 1)) & 3;
            bfr[ni] = *(const bf16x8*)&b_[row * 32 + slot * 8];
        }
#pragma unroll
        for (int mi = 0; mi < 2; ++mi)
#pragma unroll
            for (int ni = 0; ni < 6; ++ni)
                acc[mi][ni] = __builtin_amdgcn_mfma_f32_16x16x32_bf16(
                    af[mi], bfr[ni], acc[mi][ni], 0, 0, 0);
        if (ks < 5) writeA(buf ^ 1);
    }

    const int ocol = lane & 15;
    const int prow = (lane >> 4) * 4;
#pragma unroll
    for (int mi = 0; mi < 2; ++mi) {
        int pix = pix0 + wrow * 32 + mi * 16 + prow;
#pragma unroll
        for (int ni = 0; ni < 6; ++ni) {
            int o = o0 + wcol * 96 + ni * 16 + ocol;
            f32x4 v = acc[mi][ni];
            if constexpr (OUT_BF16) {
                ushort_t* Cp = (ushort_t*)C + (size_t)b * strideC + (size_t)o * HWPX + pix;
                uint2 pk;
                pk.x = (unsigned)f2bf(v[0]) | ((unsigned)f2bf(v[1]) << 16);
                pk.y = (unsigned)f2bf(v[2]) | ((unsigned)f2bf(v[3]) << 16);
                *(uint2*)Cp = pk;
            } else {
                float* Cp = (float*)C + (size_t)b * strideC + (size_t)o * HWPX + pix;
                *(float4*)Cp = make_float4(v[0], v[1], v[2], v[3]);
            }
        }
    }
}

// ---------------------------------------------------------------------------
// k_dw: depthwise 3x3 SAME + fused per-channel sum of squares.
// tile base at +8 elems (16B) so staging uint4 writes stay aligned.
// ---------------------------------------------------------------------------
__global__ __launch_bounds__(256) void k_dw(const ushort_t* __restrict__ pre,
                                            const float* __restrict__ dww,
                                            ushort_t* __restrict__ dwout,
                                            float* __restrict__ norm2) {
    __shared__ ushort_t tile_raw[HWPX + 16];
    __shared__ float red[256];
    ushort_t* tile = tile_raw + 8;
    const int ch = blockIdx.x, b = blockIdx.y;
    const int t = threadIdx.x;
    const ushort_t* in = pre + ((size_t)b * C3 + ch) * HWPX;
    ushort_t* outp = dwout + ((size_t)b * C3 + ch) * HWPX;
    float w[9];
#pragma unroll
    for (int i = 0; i < 9; ++i) w[i] = dww[ch * 9 + i];
#pragma unroll
    for (int r = 0; r < 8; ++r) {
        int f = t + r * 256;
        *(uint4*)(tile + f * 8) = *(const uint4*)(in + f * 8);
    }
    __syncthreads();
    float ssq = 0.f;
#pragma unroll 2
    for (int r = 0; r < 8; ++r) {
        int p = r * 2048 + t * 8;
        int y = p >> 7, x0 = p & 127;
        float vin[3][12];
#pragma unroll
        for (int ky = 0; ky < 3; ++ky) {
            int yy = y + ky - 1;
            bool ok = (yy >= 0) && (yy <= 127);
            int base = yy * 128 + x0 - 2;
#pragma unroll
            for (int q = 0; q < 6; ++q) {
                unsigned uu = ok ? *(const unsigned*)&tile[base + q * 2] : 0u;
                vin[ky][q * 2] = __uint_as_float(uu << 16);
                vin[ky][q * 2 + 1] = __uint_as_float(uu & 0xffff0000u);
            }
        }
        if (x0 == 0) {
#pragma unroll
            for (int ky = 0; ky < 3; ++ky) { vin[ky][0] = 0.f; vin[ky][1] = 0.f; }
        }
        if (x0 == 120) {
#pragma unroll
            for (int ky = 0; ky < 3; ++ky) { vin[ky][10] = 0.f; vin[ky][11] = 0.f; }
        }
        ushort_t outv[8];
#pragma unroll
        for (int j = 0; j < 8; ++j) {
            float s = 0.f;
#pragma unroll
            for (int ky = 0; ky < 3; ++ky) {
                s = fmaf(w[ky * 3 + 0], vin[ky][j + 1], s);
                s = fmaf(w[ky * 3 + 1], vin[ky][j + 2], s);
                s = fmaf(w[ky * 3 + 2], vin[ky][j + 3], s);
            }
            ssq = fmaf(s, s, ssq);
            outv[j] = f2bf(s);
        }
        uint4 pk;
        pk.x = (unsigned)outv[0] | ((unsigned)outv[1] << 16);
        pk.y = (unsigned)outv[2] | ((unsigned)outv[3] << 16);
        pk.z = (unsigned)outv[4] | ((unsigned)outv[5] << 16);
        pk.w = (unsigned)outv[6] | ((unsigned)outv[7] << 16);
        *(uint4*)(outp + p) = pk;
    }
    red[t] = ssq;
    __syncthreads();
    for (int s2 = 128; s2 > 0; s2 >>= 1) {
        if (t < s2) red[t] += red[t + s2];
        __syncthreads();
    }
    if (t == 0) norm2[b * C3 + ch] = red[0];
}

// ---------------------------------------------------------------------------
// k_gram: MFMA gram partials. grid (chunk=8, h, b), 4 waves x 512 px each.
// ---------------------------------------------------------------------------
__global__ __launch_bounds__(256) void k_gram(const ushort_t* __restrict__ qkv_dw,
                                              float* __restrict__ gpart) {
    __shared__ float sG[4][DH][DH];
    const int chunk = blockIdx.x, h = blockIdx.y, b = blockIdx.z;
    const int t = threadIdx.x;
    const int lane = t & 63, wave = t >> 6;
    const ushort_t* qb = qkv_dw + ((size_t)b * C3 + h * DH) * HWPX;
    const ushort_t* kb = qkv_dw + ((size_t)b * C3 + CIN + h * DH) * HWPX;
    f32x4 acc[3][3];
#pragma unroll
    for (int i = 0; i < 3; ++i)
#pragma unroll
        for (int j = 0; j < 3; ++j) acc[i][j] = (f32x4){0.f, 0.f, 0.f, 0.f};

    const int rowoff = (lane & 15);
    const int koff = (lane >> 4) * 8;
#pragma unroll 2
    for (int kp = 0; kp < 16; ++kp) {
        int pix0 = chunk * 2048 + wave * 512 + kp * 32;
        bf16x8 af[3], bk[3];
#pragma unroll
        for (int i = 0; i < 3; ++i)
            af[i] = *(const bf16x8*)(qb + (size_t)(i * 16 + rowoff) * HWPX + pix0 + koff);
#pragma unroll
        for (int j = 0; j < 3; ++j)
            bk[j] = *(const bf16x8*)(kb + (size_t)(j * 16 + rowoff) * HWPX + pix0 + koff);
#pragma unroll
        for (int i = 0; i < 3; ++i)
#pragma unroll
            for (int j = 0; j < 3; ++j)
                acc[i][j] = __builtin_amdgcn_mfma_f32_16x16x32_bf16(af[i], bk[j],
                                                                    acc[i][j], 0, 0, 0);
    }
    const int crow = (lane >> 4) * 4;
    const int dcol = lane & 15;
#pragma unroll
    for (int i = 0; i < 3; ++i)
#pragma unroll
        for (int j = 0; j < 3; ++j)
#pragma unroll
            for (int r = 0; r < 4; ++r)
                sG[wave][i * 16 + crow + r][j * 16 + dcol] = acc[i][j][r];
    __syncthreads();
    const float* sGf = &sG[0][0][0];
    float* g = gpart + (((size_t)(b * NHEADS + h)) * 8 + chunk) * (DH * DH);
#pragma unroll
    for (int e = t; e < DH * DH; e += 256)
        g[e] = sGf[e] + sGf[DH * DH + e] + sGf[2 * DH * DH + e] + sGf[3 * DH * DH + e];
}

// ---------------------------------------------------------------------------
// k_attn: reduce partials -> normalize -> softmax -> att fp32 [b][h][48][48]
// ---------------------------------------------------------------------------
__global__ __launch_bounds__(256) void k_attn(const float* __restrict__ gpart,
                                              const float* __restrict__ norm2,
                                              const float* __restrict__ temperature,
                                              float* __restrict__ att) {
    __shared__ float sA[DH][DH + 1];
    const int h = blockIdx.x, b = blockIdx.y;
    const int t = threadIdx.x;
    const float* base = gpart + ((size_t)(b * NHEADS + h) * 8) * (DH * DH);
    for (int e = t; e < DH * DH; e += 256) {
        float s = 0.f;
#pragma unroll
        for (int c8 = 0; c8 < 8; ++c8) s += base[(size_t)c8 * DH * DH + e];
        int c = e / DH, d = e % DH;
        float nq = fmaxf(sqrtf(norm2[b * C3 + h * DH + c]), 1e-12f);
        float nk = fmaxf(sqrtf(norm2[b * C3 + CIN + h * DH + d]), 1e-12f);
        sA[c][d] = s / (nq * nk) * temperature[h];
    }
    __syncthreads();
    if (t < DH) {
        float m = -1e30f;
#pragma unroll
        for (int d = 0; d < DH; ++d) m = fmaxf(m, sA[t][d]);
        float s = 0.f;
        float row[DH];
#pragma unroll
        for (int d = 0; d < DH; ++d) {
            row[d] = expf(sA[t][d] - m);
            s += row[d];
        }
        float inv = 1.f / s;
#pragma unroll
        for (int d = 0; d < DH; ++d) sA[t][d] = row[d] * inv;
    }
    __syncthreads();
    float* ob = att + ((size_t)(b * NHEADS + h)) * DH * DH;
    for (int e = t; e < DH * DH; e += 256) ob[e] = sA[e / DH][e % DH];
}

// ---------------------------------------------------------------------------
// k_mw: Mw[b][o][192] = proj_w @ blockdiag(att), bf16 out. grid (6 otile, b)
// ---------------------------------------------------------------------------
__global__ __launch_bounds__(256) void k_mw(const float* __restrict__ att,
                                            const float* __restrict__ proj_w,
                                            ushort_t* __restrict__ Mw) {
    __shared__ float satt[NHEADS][DH][DH];
    __shared__ float sproj[32][CIN];
    const int o0 = blockIdx.x * 32, b = blockIdx.y;
    const int t = threadIdx.x;
    {
        const float4* src = (const float4*)(att + (size_t)b * NHEADS * DH * DH);
        float4* dst = (float4*)&satt[0][0][0];
        for (int e = t; e < NHEADS * DH * DH / 4; e += 256) dst[e] = src[e];
        const float4* ps = (const float4*)(proj_w + (size_t)o0 * CIN);
        float4* pd = (float4*)&sproj[0][0];
        for (int e = t; e < 32 * CIN / 4; e += 256) pd[e] = ps[e];
    }
    __syncthreads();
    ushort_t* ob = Mw + (size_t)b * CIN * CIN + (size_t)o0 * CIN;
    for (int e = t; e < 32 * CIN; e += 256) {
        int o = e / CIN, dg = e % CIN;
        int h = dg / DH, d = dg % DH;
        float s = 0.f;
#pragma unroll
        for (int c = 0; c < DH; ++c) s = fmaf(sproj[o][h * DH + c], satt[h][c][d], s);
        ob[e] = f2bf(s);
    }
}

extern "C" void kernel_launch(void* const* d_in, const int* in_sizes, int n_in,
                              void* d_out, int out_size, void* d_ws, size_t ws_size,
                              hipStream_t stream) {
    const float* x = (const float*)d_in[0];
    const float* qkv_w = (const float*)d_in[1];
    const float* dw_w = (const float*)d_in[2];
    const float* proj_w = (const float*)d_in[3];
    const float* temperature = (const float*)d_in[4];
    float* out = (float*)d_out;

    char* ws = (char*)d_ws;
    // layout (bytes):
    //   [0, 150994944)           pre  bf16 [b][576][16384]
    //   [150994944, 301989888)   dwv  bf16 [b][576][16384]
    //   [301989888, +221184)     wq bf16
    //   [302211072, +18432)      norm2 fp32
    //   [302229504, +2359296)    gpart fp32
    //   [304588800, +589824)     Mw bf16
    //   [305178624, +294912)     attb fp32
    ushort_t* pre = (ushort_t*)ws;
    ushort_t* dwv = (ushort_t*)(ws + 150994944);
    ushort_t* wq = (ushort_t*)(ws + 301989888);
    float* norm2 = (float*)(ws + 302211072);
    float* gpart = (float*)(ws + 302229504);
    ushort_t* Mw = (ushort_t*)(ws + 304588800);
    float* attb = (float*)(ws + 305178624);

    const long sA_x = (long)CIN * HWPX;    // x per-batch stride (fp32 elems)
    const long sA_v = (long)C3 * HWPX;     // dwv per-batch stride (bf16 elems)
    const long sC_pre = (long)C3 * HWPX;
    const long sB_mw = (long)CIN * CIN;
    const long sC_out = (long)CIN * HWPX;

    k_cvtw<<<dim3(108), 256, 0, stream>>>(qkv_w, wq);
    k_gemm<true, true><<<dim3(128, 3, 8), 512, 0, stream>>>(
        (const void*)x, wq, (void*)pre, sA_x, 0L, sC_pre);
    k_dw<<<dim3(576, 8), 256, 0, stream>>>(pre, dw_w, dwv, norm2);
    k_gram<<<dim3(8, NHEADS, 8), 256, 0, stream>>>(dwv, gpart);
    k_attn<<<dim3(NHEADS, 8), 256, 0, stream>>>(gpart, norm2, temperature, attb);
    k_mw<<<dim3(6, 8), 256, 0, stream>>>(attb, proj_w, Mw);
    k_gemm<false, false><<<dim3(128, 1, 8), 512, 0, stream>>>(
        (const void*)(dwv + (size_t)2 * CIN * HWPX), Mw, (void*)out, sA_v, sB_mw, sC_out);
}